// Round 9
// baseline (409.286 us; speedup 1.0000x reference)
//
#include <hip/hip_runtime.h>
#include <math.h>

// Problem constants (from setup_inputs)
#define NN   2048   // nodes
#define FF   300    // input features
#define FP   320    // FF padded to 32 multiple for MFMA K
#define NH   20     // heads
#define HHID 600    // per-head hidden
#define HP   640    // HHID padded to 128 multiple for MFMA N
#define HCAT (NH * HHID)  // 12000
#define DOUT 1000   // out_att width
#define NPAD 1024   // DOUT padded to 128 multiple for MFMA GEMM
#define MLPD 1000   // MLP hidden
#define NOUTD 768   // final output
#define NE   32768  // edges
#define NG   128    // graphs
#define CAP  160    // max neighbors kept per row (Poisson(16) tail safe)
#define KSPL 8      // split-K factor for the K=12000 GEMM (1024 blocks = 4/CU)
#define KSP0 6      // partials z<KSP0 live in buffer0 (Whb), rest in buffer1 (att_c)
#define KCH  1504   // K chunk (x32); last chunk = 12000-7*1504 = 1472
#define PVC  16     // PV column chunks (gridDim.x -> XCD pin = chunk%8)
#define PVR  16     // PV rows per block
#define PVU  94     // short8-units per PV chunk (1500 total; last chunk = 90)

typedef __attribute__((ext_vector_type(8))) short short8;   // 8 bf16 (A/B frag)
typedef __attribute__((ext_vector_type(4))) float f32x4;    // C/D frag

__device__ __forceinline__ unsigned short f2bf(float f) {
  // round-to-nearest-even fp32 -> bf16
  unsigned int u = __float_as_uint(f);
  u += 0x7fffu + ((u >> 16) & 1u);
  return (unsigned short)(u >> 16);
}
__device__ __forceinline__ float bf2f(unsigned short u) {
  return __uint_as_float(((unsigned int)u) << 16);
}
__device__ __forceinline__ void st_out(float* p, float v) { *p = v; }
__device__ __forceinline__ void st_out(unsigned short* p, float v) { *p = f2bf(v); }

// ---------------- utility kernels ----------------

__global__ void zero_words(unsigned int* __restrict__ p, int n) {
  int i = blockIdx.x * blockDim.x + threadIdx.x;
  int stride = gridDim.x * blockDim.x;
  for (; i < n; i += stride) p[i] = 0u;
}

__global__ void scatter_mask(const int* __restrict__ ei, unsigned char* __restrict__ mask) {
  int e = blockIdx.x * blockDim.x + threadIdx.x;
  if (e < NE) {
    int s = ei[e], d = ei[NE + e];
    mask[(size_t)s * NN + d] = 1;
  }
}

// one wave per row: dword-load the adjacency row, ballot-compact per byte lane
__global__ void build_csr(const unsigned char* __restrict__ mask,
                          int* __restrict__ nbr, int* __restrict__ deg) {
  int wave = threadIdx.x >> 6, lane = threadIdx.x & 63;
  int i = blockIdx.x * 4 + wave;
  if (i >= NN) return;
  const unsigned* roww = (const unsigned*)(mask + (size_t)i * NN);
  int cnt = 0;
  for (int c0 = 0; c0 < NN; c0 += 256) {        // 256 bytes per iter
    unsigned word = roww[(c0 >> 2) + lane];
#pragma unroll
    for (int b = 0; b < 4; b++) {
      bool p = ((word >> (8 * b)) & 0xffu) != 0u;
      unsigned long long bal = __ballot(p);
      if (p) {
        int pos = cnt + (int)__popcll(bal & ((1ull << lane) - 1ull));
        if (pos < CAP) nbr[(size_t)i * CAP + pos] = c0 + lane * 4 + b;
      }
      cnt += (int)__popcll(bal);
    }
  }
  if (lane == 0) deg[i] = cnt < CAP ? cnt : CAP;
}

// ---------------- attention logits via associativity ----------------
// f1 = (x@W)@a1 = x@(W@a1); colsum(x@W) = colsum(x)@W — all fp32, no Whb pass.

// w1[hd][k] = sum_c W_heads[hd][k][c]*a1[hd][c] (same for w2/a2). grid (FF, NH), 64 thr.
__global__ void w12_kernel(const float* __restrict__ W, const float* __restrict__ a1,
                           const float* __restrict__ a2,
                           float* __restrict__ w1, float* __restrict__ w2) {
  int k = blockIdx.x, hd = blockIdx.y, lane = threadIdx.x;
  const float* r = W + ((size_t)hd * FF + k) * HHID;
  const float* A1 = a1 + (size_t)hd * HHID;
  const float* A2 = a2 + (size_t)hd * HHID;
  float s1 = 0.f, s2 = 0.f;
  for (int c = lane; c < HHID; c += 64) {
    float w = r[c];
    s1 += w * A1[c];
    s2 += w * A2[c];
  }
  for (int off = 32; off; off >>= 1) {
    s1 += __shfl_down(s1, off);
    s2 += __shfl_down(s2, off);
  }
  if (lane == 0) { w1[(size_t)hd * FF + k] = s1; w2[(size_t)hd * FF + k] = s2; }
}

// f1a[hd][i] = x[i,:].w1[hd], f2a likewise. grid (NN), 256 thr; x-row staged in LDS.
__global__ __launch_bounds__(256)
void f12x_kernel(const float* __restrict__ x, const float* __restrict__ w1,
                 const float* __restrict__ w2,
                 float* __restrict__ f1, float* __restrict__ f2) {
  __shared__ float xr[FF];
  int i = blockIdx.x, t = threadIdx.x;
  for (int c = t; c < FF; c += 256) xr[c] = x[(size_t)i * FF + c];
  __syncthreads();
  if (t < 2 * NH) {
    int hd = t >> 1;
    const float* wv = ((t & 1) ? w2 : w1) + (size_t)hd * FF;
    float s = 0.f;
    for (int k = 0; k < FF; k++) s += xr[k] * wv[k];
    ((t & 1) ? f2 : f1)[(size_t)hd * NN + i] = s;
  }
}

// csa[hd][c] += sum over a 60-row k-slab of xsum[k]*W_heads[hd][k][c].
// grid (cdiv(HHID,256), NH, 5) = 300 blocks, coalesced W reads; csa pre-zeroed.
__global__ __launch_bounds__(256)
void csa_at(const float* __restrict__ xsum, const float* __restrict__ W,
            float* __restrict__ csa) {
  __shared__ float xs[60];
  int hd = blockIdx.y, kz = blockIdx.z, t = threadIdx.x;
  int k0 = kz * 60;
  int nk = (k0 + 60 <= FF) ? 60 : (FF - k0);
  if (t < nk) xs[t] = xsum[k0 + t];
  __syncthreads();
  int c = blockIdx.x * 256 + t;
  if (c >= HHID) return;
  const float* Wp = W + ((size_t)hd * FF + k0) * HHID + c;
  float s = 0.f;
  for (int k = 0; k < nk; k++) s += xs[k] * Wp[(size_t)k * HHID];
  atomicAdd(&csa[(size_t)hd * HHID + c], s);
}

// ---------------- f1/f2 + colsum (fallback + out-layer) ----------------

__global__ void f12_kernel(const float* __restrict__ Wh, int ldw, int h,
                           const float* __restrict__ a1, const float* __restrict__ a2,
                           int astride,
                           float* __restrict__ f1, float* __restrict__ f2) {
  int i = blockIdx.x, hd = blockIdx.y;
  int lane = threadIdx.x;
  const float* r = Wh + (size_t)i * ldw + (size_t)hd * h;
  const float* A1 = a1 + (size_t)hd * astride;
  const float* A2 = a2 + (size_t)hd * astride;
  float s1 = 0.f, s2 = 0.f;
  for (int c = lane; c < h; c += 64) {
    float w = r[c];
    s1 += w * A1[c];
    s2 += w * A2[c];
  }
  for (int off = 32; off; off >>= 1) {
    s1 += __shfl_down(s1, off);
    s2 += __shfl_down(s2, off);
  }
  if (lane == 0) { f1[(size_t)hd * NN + i] = s1; f2[(size_t)hd * NN + i] = s2; }
}

// bf16 input, short8-vectorized; h must be divisible by 8 (out-layer on accb)
__global__ void f12_bf16(const unsigned short* __restrict__ Wh, int ldw, int h,
                         const float* __restrict__ a1, const float* __restrict__ a2,
                         int astride,
                         float* __restrict__ f1, float* __restrict__ f2) {
  int i = blockIdx.x, hd = blockIdx.y;
  int lane = threadIdx.x;
  const unsigned short* r = Wh + (size_t)i * ldw + (size_t)hd * h;
  const float* A1 = a1 + (size_t)hd * astride;
  const float* A2 = a2 + (size_t)hd * astride;
  float s1 = 0.f, s2 = 0.f;
  for (int c8 = lane; c8 < h / 8; c8 += 64) {
    short8 v = *(const short8*)(r + (size_t)c8 * 8);
#pragma unroll
    for (int j = 0; j < 8; j++) {
      float w = bf2f((unsigned short)v[j]);
      s1 += w * A1[c8 * 8 + j];
      s2 += w * A2[c8 * 8 + j];
    }
  }
  for (int off = 32; off; off >>= 1) {
    s1 += __shfl_down(s1, off);
    s2 += __shfl_down(s2, off);
  }
  if (lane == 0) { f1[(size_t)hd * NN + i] = s1; f2[(size_t)hd * NN + i] = s2; }
}

// serial colsum (fallback path only)
__global__ void colsum_kernel(const float* __restrict__ Wh, int ldw, int h,
                              float* __restrict__ cs) {
  int hd = blockIdx.y;
  int c = blockIdx.x * blockDim.x + threadIdx.x;
  if (c >= h) return;
  size_t off = (size_t)hd * h + c;
  float s = 0.f;
  for (int i = 0; i < NN; i++) s += Wh[(size_t)i * ldw + off];
  cs[(size_t)hd * h + c] = s;
}

// row-parallel colsum + atomics: grid (cdiv(width,256), rows/64); cs pre-zeroed.
__global__ void colsum_at_bf16(const unsigned short* __restrict__ Wh, int ld, int width,
                               float* __restrict__ cs) {
  int c = blockIdx.x * blockDim.x + threadIdx.x;
  if (c >= width) return;
  int r0 = blockIdx.y * 64;
  float s = 0.f;
  for (int i = r0; i < r0 + 64; i++) s += bf2f(Wh[(size_t)i * ld + c]);
  atomicAdd(&cs[c], s);
}

__global__ void colsum_at_f32(const float* __restrict__ Wh, int ld, int width,
                              float* __restrict__ cs) {
  int c = blockIdx.x * blockDim.x + threadIdx.x;
  if (c >= width) return;
  int r0 = blockIdx.y * 64;
  float s = 0.f;
  for (int i = r0; i < r0 + 64; i++) s += Wh[(size_t)i * ld + c];
  atomicAdd(&cs[c], s);
}

// ---------------- sparse attention (softmax + PV + elu) ----------------

// fp32 fallback version: one block (256 thr) per (row, head)
template <typename OT>
__global__ __launch_bounds__(256)
void spmm_att(const float* __restrict__ Wh, int ldw, int h,
              const float* __restrict__ f1, const float* __restrict__ f2,
              const int* __restrict__ nbr, const int* __restrict__ deg,
              const float* __restrict__ cs,
              OT* __restrict__ outp, int ldo) {
  __shared__ float att[CAP];
  __shared__ int   nb[CAP];
  __shared__ float red[256];
  int i = blockIdx.x, hd = blockIdx.y;
  int t = threadIdx.x;
  int d = deg[i];
  size_t hoff = (size_t)hd * h;
  if (d > 0) {
    float fi = f1[(size_t)hd * NN + i];
    const float* F2 = f2 + (size_t)hd * NN;
    float lmax = -INFINITY;
    for (int k = t; k < d; k += 256) {
      int j = nbr[(size_t)i * CAP + k];
      nb[k] = j;
      float e = fi + F2[j];
      e = e > 0.f ? e : 0.02f * e;   // leaky_relu slope 0.02
      att[k] = e;
      lmax = fmaxf(lmax, e);
    }
    red[t] = lmax; __syncthreads();
    for (int s = 128; s; s >>= 1) { if (t < s) red[t] = fmaxf(red[t], red[t + s]); __syncthreads(); }
    float m = red[0]; __syncthreads();
    float ls = 0.f;
    for (int k = t; k < d; k += 256) { float p = expf(att[k] - m); att[k] = p; ls += p; }
    red[t] = ls; __syncthreads();
    for (int s = 128; s; s >>= 1) { if (t < s) red[t] += red[t + s]; __syncthreads(); }
    float inv = 1.0f / red[0]; __syncthreads();
    for (int k = t; k < d; k += 256) att[k] *= inv;
    __syncthreads();
    for (int c = t; c < h; c += 256) {
      float s = 0.f;
      for (int k = 0; k < d; k++) s += att[k] * Wh[(size_t)nb[k] * ldw + hoff + c];
      s = s > 0.f ? s : (expf(s) - 1.0f);  // elu
      st_out(&outp[(size_t)i * ldo + hoff + c], s);
    }
  } else {
    const float inv = 1.0f / (float)NN;
    for (int c = t; c < h; c += 256) {
      float s = cs[hoff + c] * inv;
      s = s > 0.f ? s : (expf(s) - 1.0f);
      st_out(&outp[(size_t)i * ldo + hoff + c], s);
    }
  }
}

// precompute normalized attention weights: att_c[i][hd][k] (k < deg[i]).
// grid (NN, NH/4), block 256 = 4 waves; wave w -> head by*4+w.
__global__ __launch_bounds__(256)
void att_pre(const float* __restrict__ f1, const float* __restrict__ f2,
             const int* __restrict__ nbr, const int* __restrict__ deg,
             float* __restrict__ att_c) {
  __shared__ int   nb_sh[CAP];
  __shared__ float att_sh[4][CAP];
  int i = blockIdx.x;
  int t = threadIdx.x, w = t >> 6, lane = t & 63;
  int hd = blockIdx.y * 4 + w;
  int d = deg[i];
  if (d == 0) return;   // uniform across block: safe before syncthreads
  for (int k = t; k < d; k += 256) nb_sh[k] = nbr[(size_t)i * CAP + k];
  __syncthreads();
  float fi = f1[(size_t)hd * NN + i];
  const float* F2 = f2 + (size_t)hd * NN;
  float lmax = -INFINITY;
  for (int k = lane; k < d; k += 64) {
    float e = fi + F2[nb_sh[k]];
    e = e > 0.f ? e : 0.02f * e;   // leaky_relu slope 0.02
    att_sh[w][k] = e;
    lmax = fmaxf(lmax, e);
  }
  for (int off = 32; off; off >>= 1) lmax = fmaxf(lmax, __shfl_xor(lmax, off));
  float ls = 0.f;
  for (int k = lane; k < d; k += 64) {
    float p = expf(att_sh[w][k] - lmax);
    att_sh[w][k] = p; ls += p;
  }
  for (int off = 32; off; off >>= 1) ls += __shfl_xor(ls, off);
  float inv = 1.0f / ls;
  float* ao = att_c + ((size_t)i * NH + hd) * CAP;
  for (int k = lane; k < d; k += 64) ao[k] = att_sh[w][k] * inv;
}

// column-chunked PV gather + elu. grid (PVC, NN/PVR) — chunk is the FAST grid dim
// so all blocks of chunk c land on XCD c%8 (gridDim.x=16 multiple of 8).
__global__ __launch_bounds__(256)
void spmm_pv(const unsigned short* __restrict__ Whb,   // [NN][HCAT] bf16
             const float* __restrict__ att_c,          // [NN][NH][CAP]
             const int* __restrict__ nbr, const int* __restrict__ deg,
             const float* __restrict__ cs,
             unsigned short* __restrict__ outp) {      // [NN][HCAT] bf16
  __shared__ int nb_sh[PVR][CAP];
  __shared__ int d_sh[PVR];
  int t = threadIdx.x;
  int r0 = blockIdx.y * PVR;
  int u0 = blockIdx.x * PVU;
  int nu = (u0 + PVU <= HCAT / 8) ? PVU : (HCAT / 8 - u0);
  if (t < PVR) d_sh[t] = deg[r0 + t];
  for (int q = t; q < PVR * CAP; q += 256) {
    int r = q / CAP, k = q - r * CAP;
    nb_sh[r][k] = nbr[(size_t)(r0 + r) * CAP + k];
  }
  __syncthreads();
  const float invn = 1.0f / (float)NN;
  int total = PVR * nu;
  for (int q = t; q < total; q += 256) {
    int r = q / nu, u = q - r * nu;
    int i = r0 + r;
    int gu = u0 + u;                       // global short8 unit
    int hd = gu / (HHID / 8);              // 75 units per head
    int d = d_sh[r];
    const unsigned short* base = Whb + (size_t)gu * 8;
    unsigned short o8[8];
    if (d > 0) {
      const float* av = att_c + ((size_t)i * NH + hd) * CAP;
      float a8[8] = {};
      for (int k = 0; k < d; k++) {
        float a = av[k];
        short8 v = *(const short8*)(base + (size_t)nb_sh[r][k] * HCAT);
#pragma unroll
        for (int j = 0; j < 8; j++) a8[j] += a * bf2f((unsigned short)v[j]);
      }
#pragma unroll
      for (int j = 0; j < 8; j++) {
        float s = a8[j];
        s = s > 0.f ? s : (expf(s) - 1.0f);   // elu
        o8[j] = f2bf(s);
      }
    } else {
#pragma unroll
      for (int j = 0; j < 8; j++) {
        float s = cs[(size_t)gu * 8 + j] * invn;
        s = s > 0.f ? s : (expf(s) - 1.0f);
        o8[j] = f2bf(s);
      }
    }
    *(short8*)(outp + (size_t)i * HCAT + (size_t)gu * 8) = *(const short8*)o8;
  }
}

// out layer, bf16 in / fp32 out: grid (NN), block 128; 125 short8 chunks of DOUT=1000
__global__ __launch_bounds__(128)
void spmm_att_o(const unsigned short* __restrict__ Wh,   // [NN][DOUT] bf16
                const float* __restrict__ f1, const float* __restrict__ f2,
                const int* __restrict__ nbr, const int* __restrict__ deg,
                const float* __restrict__ cs,
                float* __restrict__ outp) {              // [NN][DOUT] fp32
  __shared__ int   nb_sh[CAP];
  __shared__ float att_sh[CAP];
  __shared__ float red[128];
  int i = blockIdx.x, t = threadIdx.x;
  int d = deg[i];
  if (d > 0) {
    float fi = f1[i];
    float lmax = -INFINITY;
    for (int k = t; k < d; k += 128) {
      int j = nbr[(size_t)i * CAP + k];
      nb_sh[k] = j;
      float e = fi + f2[j];
      e = e > 0.f ? e : 0.02f * e;
      att_sh[k] = e;
      lmax = fmaxf(lmax, e);
    }
    red[t] = lmax; __syncthreads();
    for (int s = 64; s; s >>= 1) { if (t < s) red[t] = fmaxf(red[t], red[t + s]); __syncthreads(); }
    float m = red[0]; __syncthreads();
    float ls = 0.f;
    for (int k = t; k < d; k += 128) { float p = expf(att_sh[k] - m); att_sh[k] = p; ls += p; }
    red[t] = ls; __syncthreads();
    for (int s = 64; s; s >>= 1) { if (t < s) red[t] += red[t + s]; __syncthreads(); }
    float inv = 1.0f / red[0]; __syncthreads();
    for (int k = t; k < d; k += 128) att_sh[k] *= inv;
    __syncthreads();
    for (int cc = t; cc < DOUT / 8; cc += 128) {
      float a8[8] = {};
      const unsigned short* base = Wh + (size_t)cc * 8;
      for (int k = 0; k < d; k++) {
        float av = att_sh[k];
        short8 v = *(const short8*)(base + (size_t)nb_sh[k] * DOUT);
#pragma unroll
      for (int j = 0; j < 8; j++)
          a8[j] += av * bf2f((unsigned short)v[j]);
      }
      float o[8];
#pragma unroll
      for (int j = 0; j < 8; j++) {
        float s = a8[j];
        o[j] = s > 0.f ? s : (expf(s) - 1.0f);
      }
      *(float4*)(outp + (size_t)i * DOUT + (size_t)cc * 8)     = make_float4(o[0], o[1], o[2], o[3]);
      *(float4*)(outp + (size_t)i * DOUT + (size_t)cc * 8 + 4) = make_float4(o[4], o[5], o[6], o[7]);
    }
  } else {
    const float invn = 1.0f / (float)NN;
    for (int c = t; c < DOUT; c += 128) {
      float s = cs[c] * invn;
      outp[(size_t)i * DOUT + c] = s > 0.f ? s : (expf(s) - 1.0f);
    }
  }
}

// ---------------- bf16 conversion kernels ----------------

// x [NN][FF] fp32 -> xb [NN][FP] bf16 (zero-padded K)
__global__ void conv_x_bf16(const float* __restrict__ x, unsigned short* __restrict__ xb) {
  int i = blockIdx.x, t = threadIdx.x;   // FP=320 threads
  float v = (t < FF) ? x[(size_t)i * FF + t] : 0.0f;
  xb[(size_t)i * FP + t] = f2bf(v);
}

// W [K][N] fp32 (z-batched, stride wz) -> Wt [Npad][ldt] bf16, Wt[n][k] = W[k][n], 0-pad.
__global__ void convT_gen(const float* __restrict__ W, unsigned short* __restrict__ Wt,
                          int K, int N, int ldw, long wz, int ldt, long tz) {
  __shared__ float tile[32][33];
  const float* Wp = W + (size_t)blockIdx.z * wz;
  unsigned short* Tp = Wt + (size_t)blockIdx.z * tz;
  int k0 = blockIdx.x * 32, n0 = blockIdx.y * 32;
  int tx = threadIdx.x, ty = threadIdx.y;
#pragma unroll
  for (int r = ty; r < 32; r += 8) {
    int kk = k0 + r, n = n0 + tx;
    tile[r][tx] = (kk < K && n < N) ? Wp[(size_t)kk * ldw + n] : 0.0f;
  }
  __syncthreads();
#pragma unroll
  for (int r = ty; r < 32; r += 8) {
    Tp[(size_t)(n0 + r) * ldt + k0 + tx] = f2bf(tile[tx][r]);
  }
}

// fp32 -> bf16 flat copy
__global__ void conv_f2b(const float* __restrict__ in, unsigned short* __restrict__ out, int n) {
  int i = blockIdx.x * blockDim.x + threadIdx.x;
  int stride = gridDim.x * blockDim.x;
  for (; i < n; i += stride) out[i] = f2bf(in[i]);
}

// ---------------- bf16 MFMA GEMM ----------------
// C = A @ Bt^T. BM=BN=128, BK=32, 256 thr = 4 waves (2x2), wave tile 64x64,
// mfma 16x16x32 bf16, global_load_lds(16B) staging. OT = float or ushort (bf16 C).
// SWZ=1: XCD-chunked block swizzle (requires nwg % 8 == 0).
// C base: z < zsplit -> C0 + z*cz; else C1 + (z-zsplit)*cz (split-K partial buffers).
template <int LDA, int LDB, int LDC, int NREAL, int KCHUNK, int KTOT, int SWZ, typename OT>
__global__ __launch_bounds__(256)
void gemm_bf16_t(const unsigned short* __restrict__ A, long az,
                 const unsigned short* __restrict__ Bt, long bz,
                 OT* __restrict__ C0, OT* __restrict__ C1, int zsplit, long cz) {
  __shared__ __align__(16) unsigned short As[128 * 32];  // [row][k] 8 KB
  __shared__ __align__(16) unsigned short Bs[128 * 32];  // [col][k] 8 KB
  int bx = blockIdx.x, by = blockIdx.y, bz_ = blockIdx.z;
  if (SWZ) {
    int gx = gridDim.x, gy = gridDim.y;
    int nwg = gx * gy * gridDim.z;
    int lin = bx + gx * (by + gy * bz_);
    int q = nwg >> 3;
    int lin2 = (lin & 7) * q + (lin >> 3);   // XCD-chunked, bijective (nwg%8==0)
    bx = lin2 % gx; by = (lin2 / gx) % gy; bz_ = lin2 / (gx * gy);
  }
  const int z = bz_;
  A  += (size_t)z * az;
  Bt += (size_t)z * bz;
  OT* C = (z < zsplit) ? (C0 + (size_t)z * cz) : (C1 + (size_t)(z - zsplit) * cz);
  int ks, ke;
  if (KCHUNK > 0) {
    ks = z * KCHUNK;
    ke = (ks + KCHUNK < KTOT) ? (ks + KCHUNK) : KTOT;
  } else {
    ks = 0; ke = KTOT;
  }
  const int t = threadIdx.x;
  const int w = t >> 6, lane = t & 63;
  const int m0 = by * 128, n0 = bx * 128;
  const int c0 = t, c1 = t + 256;
  const int ra0 = c0 >> 2, ca0 = (c0 & 3) * 8;
  const int ra1 = c1 >> 2, ca1 = (c1 & 3) * 8;
  const unsigned short* gA0 = A + (size_t)(m0 + ra0) * LDA + ca0;
  const unsigned short* gA1 = A + (size_t)(m0 + ra1) * LDA + ca1;
  const unsigned short* gB0 = Bt + (size_t)(n0 + ra0) * LDB + ca0;
  const unsigned short* gB1 = Bt + (size_t)(n0 + ra1) * LDB + ca1;
  unsigned short* lA0 = As + (size_t)w * 512;
  unsigned short* lA1 = As + (size_t)(4 + w) * 512;
  unsigned short* lB0 = Bs + (size_t)w * 512;
  unsigned short* lB1 = Bs + (size_t)(4 + w) * 512;
  const int wm = (w >> 1) * 64, wn = (w & 1) * 64;
  const int arow = lane & 15, acol = (lane >> 4) * 8;
  f32x4 acc[4][4] = {};
  for (int k = ks; k < ke; k += 32) {
    __builtin_amdgcn_global_load_lds((const __attribute__((address_space(1))) void*)(gA0 + k),
                                     (__attribute__((address_space(3))) void*)(lA0), 16, 0, 0);
    __builtin_amdgcn_global_load_lds((const __attribute__((address_space(1))) void*)(gA1 + k),
                                     (__attribute__((address_space(3))) void*)(lA1), 16, 0, 0);
    __builtin_amdgcn_global_load_lds((const __attribute__((address_space(1))) void*)(gB0 + k),
                                     (__attribute__((address_space(3))) void*)(lB0), 16, 0, 0);
    __builtin_amdgcn_global_load_lds((const __attribute__((address_space(1))) void*)(gB1 + k),
                                     (__attribute__((address_space(3))) void*)(lB1), 16, 0, 0);
    __syncthreads();
    short8 a[4], b[4];
#pragma unroll
    for (int i = 0; i < 4; i++)
      a[i] = *(const short8*)&As[(wm + i * 16 + arow) * 32 + acol];
#pragma unroll
    for (int j = 0; j < 4; j++)
      b[j] = *(const short8*)&Bs[(wn + j * 16 + arow) * 32 + acol];
#pragma unroll
    for (int i = 0; i < 4; i++)
#pragma unroll
      for (int j = 0; j < 4; j++)
        acc[i][j] = __builtin_amdgcn_mfma_f32_16x16x32_bf16(a[i], b[j], acc[i][j], 0, 0, 0);
    __syncthreads();
  }
  // C/D layout (m89-verified): col = lane&15, row = (lane>>4)*4 + reg
  const int crow = (lane >> 4) * 4, ccol = lane & 15;
#pragma unroll
  for (int i = 0; i < 4; i++)
#pragma unroll
    for (int j = 0; j < 4; j++) {
      int gc = n0 + wn + j * 16 + ccol;
      if (gc < NREAL) {
#pragma unroll
        for (int r = 0; r < 4; r++)
          st_out(&C[(size_t)(m0 + wm + i * 16 + crow + r) * LDC + gc], acc[i][j][r]);
      }
    }
}

// sum KSPL split-K partials (KSP0 in p0, rest in p1) -> bf16 accb
__global__ void addn_kernel(const float* __restrict__ p0, const float* __restrict__ p1,
                            unsigned short* __restrict__ ob) {
  const int n = NN * DOUT;
  int i = blockIdx.x * blockDim.x + threadIdx.x;
  int stride = gridDim.x * blockDim.x;
  for (; i < n; i += stride) {
    float v = 0.f;
#pragma unroll
    for (int z = 0; z < KSP0; z++) v += p0[(size_t)z * n + i];
#pragma unroll
    for (int z = 0; z < KSPL - KSP0; z++) v += p1[(size_t)z * n + i];
    ob[i] = f2bf(v);
  }
}

// ---------------- thin-M fp32 GEMM (MLP head: M=128) ----------------
template <int K, int KS>
__global__ __launch_bounds__(256)
void gemm_thin(const float* __restrict__ A, const float* __restrict__ B,
               float* __restrict__ P, int N) {
  constexpr int KC = K / KS;            // 125 for K=1000, KS=8
  __shared__ float Ash[128][KC + 3];
  int t = threadIdx.x;
  int tx = t & 63, ty = t >> 6;
  int n0 = blockIdx.x * 64, kz = blockIdx.y;
  int ks = kz * KC;
  for (int idx = t; idx < 128 * KC; idx += 256) {
    int r = idx / KC, c = idx - r * KC;
    Ash[r][c] = A[(size_t)r * K + ks + c];
  }
  __syncthreads();
  int nn = n0 + tx; if (nn > N - 1) nn = N - 1;   // clamp B loads (write guarded)
  const float* Bp = B + (size_t)ks * N + nn;
  int m0 = ty * 32;
  float acc[32] = {};
  for (int k4 = 0; k4 < KC / 4; k4++) {
    int k = k4 * 4;
    float w0 = Bp[(size_t)(k + 0) * N];
    float w1 = Bp[(size_t)(k + 1) * N];
    float w2 = Bp[(size_t)(k + 2) * N];
    float w3 = Bp[(size_t)(k + 3) * N];
#pragma unroll
    for (int mm = 0; mm < 32; mm++) {
      float4 a = *(const float4*)&Ash[m0 + mm][k];
      acc[mm] += a.x * w0 + a.y * w1 + a.z * w2 + a.w * w3;
    }
  }
#pragma unroll
  for (int k = (KC / 4) * 4; k < KC; k++) {
    float w0 = Bp[(size_t)k * N];
#pragma unroll
    for (int mm = 0; mm < 32; mm++) acc[mm] += Ash[m0 + mm][k] * w0;
  }
  if (n0 + tx < N) {
    float* Pp = P + (size_t)kz * 128 * N;
#pragma unroll
    for (int mm = 0; mm < 32; mm++)
      Pp[(size_t)(m0 + mm) * N + n0 + tx] = acc[mm];
  }
}

// reduce KS partials + bias (+relu if EPI==2)
template <int N, int KS, int EPI>
__global__ void thin_reduce(const float* __restrict__ P, const float* __restrict__ bias,
                            float* __restrict__ C) {
  int i = blockIdx.x * blockDim.x + threadIdx.x;
  const int total = 128 * N;
  if (i >= total) return;
  int n = i % N;
  float v = 0.f;
#pragma unroll
  for (int z = 0; z < KS; z++) v += P[(size_t)z * total + i];
  v += bias[n];
  if (EPI == 2) v = v > 0.f ? v : 0.f;
  C[i] = v;
}

// ---------------- tiled fp32 GEMM (fallback path only) ----------------
template <int BM_, int BN_, int EPI>
__global__ __launch_bounds__(256)
void gemm_t(const float* __restrict__ A, const float* __restrict__ B,
            float* __restrict__ C, const float* __restrict__ bias,
            int M, int N, int K, int lda, int ldb, int ldc, int accum,
            long bz, long cz) {
  constexpr int MR = BM_ / 16, NR = BN_ / 16;
  __shared__ float As[16][BM_ + 4];
  __shared__ float Bs[16][BN_ + 4];
  const float* Bp = B + (size_t)blockIdx.z * bz;
  float* Cp = C + (size_t)blockIdx.z * cz;
  int tx = threadIdx.x, ty = threadIdx.y;
  int tid = ty * 16 + tx;
  int m0 = blockIdx.y * BM_, n0 = blockIdx.x * BN_;
  float acc[MR][NR] = {};
  for (int k0 = 0; k0 < K; k0 += 16) {
#pragma unroll
    for (int p = 0; p < BM_ / 64; p++) {
      int id = tid + p * 256;
      int r = id >> 2, c4 = (id & 3) * 4;
      int gm = m0 + r;
      float v[4];
      if (gm < M && k0 + c4 + 3 < K) {
        const float4 t4 = *(const float4*)&A[(size_t)gm * lda + k0 + c4];
        v[0] = t4.x; v[1] = t4.y; v[2] = t4.z; v[3] = t4.w;
      } else {
#pragma unroll
        for (int q = 0; q < 4; q++) {
          int gk = k0 + c4 + q;
          v[q] = (gm < M && gk < K) ? A[(size_t)gm * lda + gk] : 0.0f;
        }
      }
#pragma unroll
      for (int q = 0; q < 4; q++) As[c4 + q][r] = v[q];
    }
#pragma unroll
    for (int p = 0; p < BN_ / 64; p++) {
      int id = tid + p * 256;
      int r = id / (BN_ / 4), c4 = (id % (BN_ / 4)) * 4;
      int gk = k0 + r, gn = n0 + c4;
      float v[4];
      if (gk < K && gn + 3 < N) {
        const float4 t4 = *(const float4*)&Bp[(size_t)gk * ldb + gn];
        v[0] = t4.x; v[1] = t4.y; v[2] = t4.z; v[3] = t4.w;
      } else {
#pragma unroll
        for (int q = 0; q < 4; q++)
          v[q] = (gk < K && gn + q < N) ? Bp[(size_t)gk * ldb + gn + q] : 0.0f;
      }
      *(float4*)&Bs[r][c4] = *(const float4*)v;
    }
    __syncthreads();
#pragma unroll
    for (int kk = 0; kk < 16; kk++) {
      float a[MR], b[NR];
#pragma unroll
      for (int q = 0; q < MR / 4; q++)
        *(float4*)&a[q * 4] = *(const float4*)&As[kk][ty * MR + q * 4];
#pragma unroll
      for (int q = 0; q < NR / 4; q++)
        *(float4*)&b[q * 4] = *(const float4*)&Bs[kk][tx * NR + q * 4];
#pragma unroll
      for (int i = 0; i < MR; i++)
#pragma unroll
        for (int j = 0; j < NR; j++) acc[i][j] += a[i] * b[j];
    }
    __syncthreads();
  }
#pragma unroll
  for (int i = 0; i < MR; i++) {
    int gm = m0 + ty * MR + i;
    if (gm >= M) continue;
#pragma unroll
    for (int j = 0; j < NR; j++) {
      int gn = n0 + tx * NR + j;
      if (gn >= N) continue;
      float r = acc[i][j];
      if (accum) r += Cp[(size_t)gm * ldc + gn];
      if (EPI == 2) { r += bias[gn]; r = r > 0.f ? r : 0.f; }
      else if (EPI == 3) { r += bias[gn]; }
      Cp[(size_t)gm * ldc + gn] = r;
    }
  }
}

// ---------------- pooling ----------------

__global__ void pool_prep(const int* __restrict__ batch, int* __restrict__ startg, int* __restrict__ cntg) {
  int n = blockIdx.x * blockDim.x + threadIdx.x;
  if (n >= NN) return;
  int b = batch[n];
  if (n == 0 || batch[n - 1] != b) startg[b] = n;
  atomicAdd(&cntg[b], 1);
}

__global__ void pool_kernel(const float* __restrict__ outb,
                            const int* __restrict__ startg, const int* __restrict__ cntg,
                            float* __restrict__ pooled) {
  int g = blockIdx.x, t = threadIdx.x;
  int st = startg[g], c = cntg[g];
  for (int ch = t; ch < DOUT; ch += 256) {
    float s = 0.f;
    for (int k = 0; k < c; k++) s += outb[(size_t)(st + k) * DOUT + ch];
    pooled[(size_t)g * DOUT + ch] = s / (float)(c > 0 ? c : 1);
  }
}

// ---------------- launch ----------------

static inline int cdiv(int a, int b) { return (a + b - 1) / b; }

extern "C" void kernel_launch(void* const* d_in, const int* in_sizes, int n_in,
                              void* d_out, int out_size, void* d_ws, size_t ws_size,
                              hipStream_t stream) {
  const float* x        = (const float*)d_in[0];
  const int*   ei       = (const int*)d_in[1];
  const int*   batch    = (const int*)d_in[2];
  const float* W_heads  = (const float*)d_in[3];
  const float* a1_heads = (const float*)d_in[4];
  const float* a2_heads = (const float*)d_in[5];
  const float* W_out    = (const float*)d_in[6];
  const float* a1_out   = (const float*)d_in[7];
  const float* a2_out   = (const float*)d_in[8];
  const float* W1       = (const float*)d_in[9];
  const float* b1       = (const float*)d_in[10];
  const float* W2       = (const float*)d_in[11];
  const float* b2       = (const float*)d_in[12];
  float* outd = (float*)d_out;
  (void)in_sizes; (void)n_in; (void)out_size;

  char* w = (char*)d_ws;
  size_t off = 0;
  auto alloc = [&](size_t bytes) {
    void* p = w + off;
    off += (bytes + 255) & ~(size_t)255;
    return p;
  };
  auto al = [](size_t b) { return (b + 255) & ~(size_t)255; };

  // common small buffers
  unsigned char* mask = (unsigned char*)alloc((size_t)NN * NN);      // 4 MB
  int*   nbr    = (int*)alloc((size_t)NN * CAP * 4);                 // 1.3 MB
  int*   deg    = (int*)alloc((size_t)NN * 4);
  float* acc    = (float*)alloc((size_t)NN * DOUT * 4);              // 8.2 MB (fallback + MLP partials)
  unsigned short* accb = (unsigned short*)alloc((size_t)NN * DOUT * 2); // 4.1 MB
  float* outb   = (float*)alloc((size_t)NN * DOUT * 4);              // 8.2 MB
  float* f1o    = (float*)alloc((size_t)NN * 4);
  float* f2o    = (float*)alloc((size_t)NN * 4);
  float* cso    = (float*)alloc((size_t)DOUT * 4);
  float* pooled = (float*)alloc((size_t)NG * DOUT * 4);
  float* hid    = (float*)alloc((size_t)NG * MLPD * 4);
  int*   startg = (int*)alloc((size_t)NG * 4);
  int*   cntg   = (int*)alloc((size_t)NG * 4);
  size_t off_common = off;

  // batched-path big buffers
  size_t need_batched = off_common
      + al((size_t)NN * HCAT * 2)           // Whb (bf16) / split-K partials z<6
      + al((size_t)NN * HCAT * 2)           // hcat bf16
      + al((size_t)NPAD * HCAT * 2)         // W_out^T bf16 (padded)
      + al((size_t)NN * FP * 2)             // x bf16
      + al((size_t)NH * HP * FP * 2)        // W_heads^T bf16
      + al((size_t)NN * NH * CAP * 4)       // att_c / split-K partials z>=6
      + al((size_t)NH * NN * 4) * 2         // f1_all + f2_all
      + al((size_t)NH * HHID * 4)           // cs_all
      + al((size_t)NH * FF * 4) * 2         // w1b + w2b
      + al((size_t)FF * 4);                 // xsum
  bool batched = ws_size >= need_batched;

  // 1) adjacency mask + CSR (dedupes duplicate edges like .at[].set(1.0))
  zero_words<<<4096, 256, 0, stream>>>((unsigned int*)mask, NN * NN / 4);
  scatter_mask<<<cdiv(NE, 256), 256, 0, stream>>>(ei, mask);
  build_csr<<<NN / 4, 256, 0, stream>>>(mask, nbr, deg);

  if (batched) {
    unsigned short* Whb   = (unsigned short*)alloc((size_t)NN * HCAT * 2);  // 49.2 MB
    unsigned short* hcatb = (unsigned short*)alloc((size_t)NN * HCAT * 2);  // 49.2 MB
    unsigned short* Wt    = (unsigned short*)alloc((size_t)NPAD * HCAT * 2);// 24.6 MB
    unsigned short* xb    = (unsigned short*)alloc((size_t)NN * FP * 2);    // 1.3 MB
    unsigned short* Wth   = (unsigned short*)alloc((size_t)NH * HP * FP * 2);// 8.2 MB
    float* att_c  = (float*)alloc((size_t)NN * NH * CAP * 4);               // 26.2 MB
    float* f1a    = (float*)alloc((size_t)NH * NN * 4);
    float* f2a    = (float*)alloc((size_t)NH * NN * 4);
    float* csa    = (float*)alloc((size_t)NH * HHID * 4);
    float* w1b    = (float*)alloc((size_t)NH * FF * 4);
    float* w2b    = (float*)alloc((size_t)NH * FF * 4);
    float* xsum   = (float*)alloc((size_t)FF * 4);
    // split-K partials: z=0..5 in Whb (6*8.19=49.15 <= 49.2 MB),
    // z=6..7 in att_c (2*8.19=16.4 <= 26.2 MB) — both dead after spmm_pv.
    float* partC0 = (float*)Whb;
    float* partC1 = att_c;

    // 2) Whb[:, hd*600:+600] = bf16(x @ W_heads[hd]) via MFMA, one launch z=heads
    conv_x_bf16<<<NN, FP, 0, stream>>>(x, xb);
    convT_gen<<<dim3(FP / 32, HP / 32, NH), dim3(32, 8), 0, stream>>>(
        W_heads, Wth, FF, HHID, HHID, (long)FF * HHID, FP, (long)HP * FP);
    gemm_bf16_t<FP, FP, HCAT, HHID, 0, FP, 1, unsigned short>
        <<<dim3(HP / 128, NN / 128, NH), 256, 0, stream>>>(
        xb, 0L, Wth, (long)HP * FP, Whb, Whb, NH, (long)HHID);
    // 3) attention logits via associativity (fp32, no Whb pass):
    //    f1 = x@(W@a1); csa = colsum(x)@W
    w12_kernel<<<dim3(FF, NH), 64, 0, stream>>>(W_heads, a1_heads, a2_heads, w1b, w2b);
    f12x_kernel<<<NN, 256, 0, stream>>>(x, w1b, w2b, f1a, f2a);
    zero_words<<<1, 256, 0, stream>>>((unsigned int*)xsum, FF);
    colsum_at_f32<<<dim3(cdiv(FF, 256), NN / 64), 256, 0, stream>>>(x, FF, FF, xsum);
    zero_words<<<12, 256, 0, stream>>>((unsigned int*)csa, NH * HHID);
    csa_at<<<dim3(cdiv(HHID, 256), NH, 5), 256, 0, stream>>>(xsum, W_heads, csa);
    // 3b) W_out -> bf16 transposed (B^T layout for contiguous MFMA B-frags)
    convT_gen<<<dim3(HCAT / 32, NPAD / 32, 1), dim3(32, 8), 0, stream>>>(
        W_out, Wt, HCAT, DOUT, DOUT, 0L, HCAT, 0L);
    // 4) softmax precompute + column-chunked PV gather (chunk->XCD L2 pin)
    att_pre<<<dim3(NN, NH / 4), 256, 0, stream>>>(f1a, f2a, nbr, deg, att_c);
    spmm_pv<<<dim3(PVC, NN / PVR), 256, 0, stream>>>(Whb, att_c, nbr, deg, csa, hcatb);
    // 5) acc = hcat @ W_out via bf16 MFMA, split-K=8 (1024 blocks = 4/CU, XCD swizzle)
    gemm_bf16_t<HCAT, HCAT, DOUT, DOUT, KCH, HCAT, 1, float>
        <<<dim3(NPAD / 128, NN / 128, KSPL), 256, 0, stream>>>(
        hcatb, 0L, Wt, 0L, partC0, partC1, KSP0, (long)NN * DOUT);
    addn_kernel<<<2048, 256, 0, stream>>>(partC0, partC1, accb);
    // 6) output attention layer (all-bf16 inputs)
    f12_bf16<<<dim3(NN, 1), 64, 0, stream>>>(accb, DOUT, DOUT, a1_out, a2_out, 0, f1o, f2o);
    zero_words<<<1, 256, 0, stream>>>((unsigned int*)cso, DOUT);
    colsum_at_bf16<<<dim3(cdiv(DOUT, 256), NN / 64), 256, 0, stream>>>(accb, DOUT, DOUT, cso);
    spmm_att_o<<<dim3(NN), 128, 0, stream>>>(accb, f1o, f2o, nbr, deg, cso, outb);
  } else {
    // fallback: per-head pipeline (fp32 GEMM + fp32 spmm)
    float* Wh   = (float*)alloc((size_t)NN * HHID * 4);
    float* hout = (float*)alloc((size_t)NN * HHID * 4);
    float* f1   = (float*)alloc((size_t)NN * 4);
    float* f2   = (float*)alloc((size_t)NN * 4);
    float* cs   = (float*)alloc((size_t)HHID * 4);
    zero_words<<<8000, 256, 0, stream>>>((unsigned int*)acc, NN * DOUT);
    for (int hd = 0; hd < NH; hd++) {
      gemm_t<64, 64, 0><<<dim3(cdiv(HHID, 64), cdiv(NN, 64), 1), dim3(16, 16), 0, stream>>>(
          x, W_heads + (size_t)hd * FF * HHID, Wh, nullptr,
          NN, HHID, FF, FF, HHID, HHID, 0, 0L, 0L);
      f12_kernel<<<dim3(NN, 1), 64, 0, stream>>>(Wh, HHID, HHID,
          a1_heads + (size_t)hd * HHID, a2_heads + (size_t)hd * HHID, 0, f1, f2);
      colsum_kernel<<<dim3(cdiv(HHID, 256), 1), 256, 0, stream>>>(Wh, HHID, HHID, cs);
      spmm_att<float><<<dim3(NN, 1), 256, 0, stream>>>(Wh, HHID, HHID, f1, f2,
                                                       nbr, deg, cs, hout, HHID);
      gemm_t<64, 64, 0><<<dim3(cdiv(DOUT, 64), cdiv(NN, 64), 1), dim3(16, 16), 0, stream>>>(
          hout, W_out + (size_t)hd * HHID * DOUT, acc, nullptr,
          NN, DOUT, HHID, HHID, DOUT, DOUT, 1, 0L, 0L);
    }
    conv_f2b<<<2048, 256, 0, stream>>>(acc, accb, NN * DOUT);
    // 6) output attention layer (fp32 logits from acc)
    f12_kernel<<<dim3(NN, 1), 64, 0, stream>>>(acc, DOUT, DOUT, a1_out, a2_out, 0, f1o, f2o);
    zero_words<<<1, 256, 0, stream>>>((unsigned int*)cso, DOUT);
    colsum_at_f32<<<dim3(cdiv(DOUT, 256), NN / 64), 256, 0, stream>>>(acc, DOUT, DOUT, cso);
    spmm_att_o<<<dim3(NN), 128, 0, stream>>>(accb, f1o, f2o, nbr, deg, cso, outb);
  }

  // 7) global mean pool (batch is sorted)
  zero_words<<<1, 256, 0, stream>>>((unsigned int*)startg, NG * 2);  // startg+cntg contiguous
  pool_prep<<<NN / 256, 256, 0, stream>>>(batch, startg, cntg);
  pool_kernel<<<NG, 256, 0, stream>>>(outb, startg, cntg, pooled);

  // 8) MLP head — thin-M split-K GEMMs (acc is dead here in both paths; reuse for partials)
  float* mlpP = acc;   // 8*128*1000*4 = 4.1 MB <= 8.2 MB
  gemm_thin<DOUT, 8><<<dim3(cdiv(MLPD, 64), 8), 256, 0, stream>>>(pooled, W1, mlpP, MLPD);
  thin_reduce<MLPD, 8, 2><<<cdiv(NG * MLPD, 256), 256, 0, stream>>>(mlpP, b1, hid);
  gemm_thin<MLPD, 8><<<dim3(cdiv(NOUTD, 64), 8), 256, 0, stream>>>(hid, W2, mlpP, NOUTD);
  thin_reduce<NOUTD, 8, 3><<<cdiv(NG * NOUTD, 256), 256, 0, stream>>>(mlpP, b2, outd);
}

// Round 10
// 394.338 us; speedup vs baseline: 1.0379x; 1.0379x over previous
//
#include <hip/hip_runtime.h>
#include <math.h>

// Problem constants (from setup_inputs)
#define NN   2048   // nodes
#define FF   300    // input features
#define FP   320    // FF padded to 32 multiple for MFMA K
#define NH   20     // heads
#define HHID 600    // per-head hidden
#define HP   640    // HHID padded to 128 multiple for MFMA N
#define HCAT (NH * HHID)  // 12000
#define DOUT 1000   // out_att width
#define NPAD 1024   // DOUT padded to 128 multiple for MFMA GEMM
#define MLPD 1000   // MLP hidden
#define NOUTD 768   // final output
#define NE   32768  // edges
#define NG   128    // graphs
#define CAP  160    // max neighbors kept per row (Poisson(16) tail safe)
#define KSPL 6      // split-K factor for the K=12000 GEMM (768 blocks = 3/CU; 8 regressed, r8)
#define KSP0 6      // all partials live in buffer0 (Whb): 6*8.19 MB <= 49.2 MB
#define KCH  2016   // K chunk (x32); last chunk = 12000-5*2016 = 1920
#define PVC  16     // PV column chunks (gridDim.x -> XCD pin = chunk%8)
#define PVR  16     // PV rows per block
#define PVU  94     // short8-units per PV chunk (1500 total; last chunk = 90)

typedef __attribute__((ext_vector_type(8))) short short8;   // 8 bf16 (A/B frag)
typedef __attribute__((ext_vector_type(4))) float f32x4;    // C/D frag

__device__ __forceinline__ unsigned short f2bf(float f) {
  // round-to-nearest-even fp32 -> bf16
  unsigned int u = __float_as_uint(f);
  u += 0x7fffu + ((u >> 16) & 1u);
  return (unsigned short)(u >> 16);
}
__device__ __forceinline__ float bf2f(unsigned short u) {
  return __uint_as_float(((unsigned int)u) << 16);
}
__device__ __forceinline__ void st_out(float* p, float v) { *p = v; }
__device__ __forceinline__ void st_out(unsigned short* p, float v) { *p = f2bf(v); }

// ---------------- utility kernels ----------------

__global__ void zero_words(unsigned int* __restrict__ p, int n) {
  int i = blockIdx.x * blockDim.x + threadIdx.x;
  int stride = gridDim.x * blockDim.x;
  for (; i < n; i += stride) p[i] = 0u;
}

__global__ void scatter_mask(const int* __restrict__ ei, unsigned char* __restrict__ mask) {
  int e = blockIdx.x * blockDim.x + threadIdx.x;
  if (e < NE) {
    int s = ei[e], d = ei[NE + e];
    mask[(size_t)s * NN + d] = 1;
  }
}

// one wave per row: dword-load the adjacency row, ballot-compact per byte lane
__global__ void build_csr(const unsigned char* __restrict__ mask,
                          int* __restrict__ nbr, int* __restrict__ deg) {
  int wave = threadIdx.x >> 6, lane = threadIdx.x & 63;
  int i = blockIdx.x * 4 + wave;
  if (i >= NN) return;
  const unsigned* roww = (const unsigned*)(mask + (size_t)i * NN);
  int cnt = 0;
  for (int c0 = 0; c0 < NN; c0 += 256) {        // 256 bytes per iter
    unsigned word = roww[(c0 >> 2) + lane];
#pragma unroll
    for (int b = 0; b < 4; b++) {
      bool p = ((word >> (8 * b)) & 0xffu) != 0u;
      unsigned long long bal = __ballot(p);
      if (p) {
        int pos = cnt + (int)__popcll(bal & ((1ull << lane) - 1ull));
        if (pos < CAP) nbr[(size_t)i * CAP + pos] = c0 + lane * 4 + b;
      }
      cnt += (int)__popcll(bal);
    }
  }
  if (lane == 0) deg[i] = cnt < CAP ? cnt : CAP;
}

// ---------------- attention logits via associativity ----------------
// f1 = (x@W)@a1 = x@(W@a1); colsum(x@W) = colsum(x)@W — all fp32, no Whb pass.

// w1[hd][k] = sum_c W_heads[hd][k][c]*a1[hd][c] (same for w2/a2). grid (FF, NH), 64 thr.
__global__ void w12_kernel(const float* __restrict__ W, const float* __restrict__ a1,
                           const float* __restrict__ a2,
                           float* __restrict__ w1, float* __restrict__ w2) {
  int k = blockIdx.x, hd = blockIdx.y, lane = threadIdx.x;
  const float* r = W + ((size_t)hd * FF + k) * HHID;
  const float* A1 = a1 + (size_t)hd * HHID;
  const float* A2 = a2 + (size_t)hd * HHID;
  float s1 = 0.f, s2 = 0.f;
  for (int c = lane; c < HHID; c += 64) {
    float w = r[c];
    s1 += w * A1[c];
    s2 += w * A2[c];
  }
  for (int off = 32; off; off >>= 1) {
    s1 += __shfl_down(s1, off);
    s2 += __shfl_down(s2, off);
  }
  if (lane == 0) { w1[(size_t)hd * FF + k] = s1; w2[(size_t)hd * FF + k] = s2; }
}

// f1a[hd][i] = x[i,:].w1[hd], f2a likewise. grid (NN), 256 thr; x-row staged in LDS.
__global__ __launch_bounds__(256)
void f12x_kernel(const float* __restrict__ x, const float* __restrict__ w1,
                 const float* __restrict__ w2,
                 float* __restrict__ f1, float* __restrict__ f2) {
  __shared__ float xr[FF];
  int i = blockIdx.x, t = threadIdx.x;
  for (int c = t; c < FF; c += 256) xr[c] = x[(size_t)i * FF + c];
  __syncthreads();
  if (t < 2 * NH) {
    int hd = t >> 1;
    const float* wv = ((t & 1) ? w2 : w1) + (size_t)hd * FF;
    float s = 0.f;
    for (int k = 0; k < FF; k++) s += xr[k] * wv[k];
    ((t & 1) ? f2 : f1)[(size_t)hd * NN + i] = s;
  }
}

// csa[hd][c] += sum over a 60-row k-slab of xsum[k]*W_heads[hd][k][c].
// grid (cdiv(HHID,256), NH, 5) = 300 blocks, coalesced W reads; csa pre-zeroed.
__global__ __launch_bounds__(256)
void csa_at(const float* __restrict__ xsum, const float* __restrict__ W,
            float* __restrict__ csa) {
  __shared__ float xs[60];
  int hd = blockIdx.y, kz = blockIdx.z, t = threadIdx.x;
  int k0 = kz * 60;
  int nk = (k0 + 60 <= FF) ? 60 : (FF - k0);
  if (t < nk) xs[t] = xsum[k0 + t];
  __syncthreads();
  int c = blockIdx.x * 256 + t;
  if (c >= HHID) return;
  const float* Wp = W + ((size_t)hd * FF + k0) * HHID + c;
  float s = 0.f;
  for (int k = 0; k < nk; k++) s += xs[k] * Wp[(size_t)k * HHID];
  atomicAdd(&csa[(size_t)hd * HHID + c], s);
}

// ---------------- f1/f2 + colsum (fallback + out-layer) ----------------

__global__ void f12_kernel(const float* __restrict__ Wh, int ldw, int h,
                           const float* __restrict__ a1, const float* __restrict__ a2,
                           int astride,
                           float* __restrict__ f1, float* __restrict__ f2) {
  int i = blockIdx.x, hd = blockIdx.y;
  int lane = threadIdx.x;
  const float* r = Wh + (size_t)i * ldw + (size_t)hd * h;
  const float* A1 = a1 + (size_t)hd * astride;
  const float* A2 = a2 + (size_t)hd * astride;
  float s1 = 0.f, s2 = 0.f;
  for (int c = lane; c < h; c += 64) {
    float w = r[c];
    s1 += w * A1[c];
    s2 += w * A2[c];
  }
  for (int off = 32; off; off >>= 1) {
    s1 += __shfl_down(s1, off);
    s2 += __shfl_down(s2, off);
  }
  if (lane == 0) { f1[(size_t)hd * NN + i] = s1; f2[(size_t)hd * NN + i] = s2; }
}

// bf16 input, short8-vectorized; h must be divisible by 8 (out-layer on accb)
__global__ void f12_bf16(const unsigned short* __restrict__ Wh, int ldw, int h,
                         const float* __restrict__ a1, const float* __restrict__ a2,
                         int astride,
                         float* __restrict__ f1, float* __restrict__ f2) {
  int i = blockIdx.x, hd = blockIdx.y;
  int lane = threadIdx.x;
  const unsigned short* r = Wh + (size_t)i * ldw + (size_t)hd * h;
  const float* A1 = a1 + (size_t)hd * astride;
  const float* A2 = a2 + (size_t)hd * astride;
  float s1 = 0.f, s2 = 0.f;
  for (int c8 = lane; c8 < h / 8; c8 += 64) {
    short8 v = *(const short8*)(r + (size_t)c8 * 8);
#pragma unroll
    for (int j = 0; j < 8; j++) {
      float w = bf2f((unsigned short)v[j]);
      s1 += w * A1[c8 * 8 + j];
      s2 += w * A2[c8 * 8 + j];
    }
  }
  for (int off = 32; off; off >>= 1) {
    s1 += __shfl_down(s1, off);
    s2 += __shfl_down(s2, off);
  }
  if (lane == 0) { f1[(size_t)hd * NN + i] = s1; f2[(size_t)hd * NN + i] = s2; }
}

// serial colsum (fallback path only)
__global__ void colsum_kernel(const float* __restrict__ Wh, int ldw, int h,
                              float* __restrict__ cs) {
  int hd = blockIdx.y;
  int c = blockIdx.x * blockDim.x + threadIdx.x;
  if (c >= h) return;
  size_t off = (size_t)hd * h + c;
  float s = 0.f;
  for (int i = 0; i < NN; i++) s += Wh[(size_t)i * ldw + off];
  cs[(size_t)hd * h + c] = s;
}

// row-parallel colsum + atomics: grid (cdiv(width,256), rows/64); cs pre-zeroed.
__global__ void colsum_at_bf16(const unsigned short* __restrict__ Wh, int ld, int width,
                               float* __restrict__ cs) {
  int c = blockIdx.x * blockDim.x + threadIdx.x;
  if (c >= width) return;
  int r0 = blockIdx.y * 64;
  float s = 0.f;
  for (int i = r0; i < r0 + 64; i++) s += bf2f(Wh[(size_t)i * ld + c]);
  atomicAdd(&cs[c], s);
}

__global__ void colsum_at_f32(const float* __restrict__ Wh, int ld, int width,
                              float* __restrict__ cs) {
  int c = blockIdx.x * blockDim.x + threadIdx.x;
  if (c >= width) return;
  int r0 = blockIdx.y * 64;
  float s = 0.f;
  for (int i = r0; i < r0 + 64; i++) s += Wh[(size_t)i * ld + c];
  atomicAdd(&cs[c], s);
}

// ---------------- sparse attention (softmax + PV + elu) ----------------

// fp32 fallback version: one block (256 thr) per (row, head)
template <typename OT>
__global__ __launch_bounds__(256)
void spmm_att(const float* __restrict__ Wh, int ldw, int h,
              const float* __restrict__ f1, const float* __restrict__ f2,
              const int* __restrict__ nbr, const int* __restrict__ deg,
              const float* __restrict__ cs,
              OT* __restrict__ outp, int ldo) {
  __shared__ float att[CAP];
  __shared__ int   nb[CAP];
  __shared__ float red[256];
  int i = blockIdx.x, hd = blockIdx.y;
  int t = threadIdx.x;
  int d = deg[i];
  size_t hoff = (size_t)hd * h;
  if (d > 0) {
    float fi = f1[(size_t)hd * NN + i];
    const float* F2 = f2 + (size_t)hd * NN;
    float lmax = -INFINITY;
    for (int k = t; k < d; k += 256) {
      int j = nbr[(size_t)i * CAP + k];
      nb[k] = j;
      float e = fi + F2[j];
      e = e > 0.f ? e : 0.02f * e;   // leaky_relu slope 0.02
      att[k] = e;
      lmax = fmaxf(lmax, e);
    }
    red[t] = lmax; __syncthreads();
    for (int s = 128; s; s >>= 1) { if (t < s) red[t] = fmaxf(red[t], red[t + s]); __syncthreads(); }
    float m = red[0]; __syncthreads();
    float ls = 0.f;
    for (int k = t; k < d; k += 256) { float p = expf(att[k] - m); att[k] = p; ls += p; }
    red[t] = ls; __syncthreads();
    for (int s = 128; s; s >>= 1) { if (t < s) red[t] += red[t + s]; __syncthreads(); }
    float inv = 1.0f / red[0]; __syncthreads();
    for (int k = t; k < d; k += 256) att[k] *= inv;
    __syncthreads();
    for (int c = t; c < h; c += 256) {
      float s = 0.f;
      for (int k = 0; k < d; k++) s += att[k] * Wh[(size_t)nb[k] * ldw + hoff + c];
      s = s > 0.f ? s : (expf(s) - 1.0f);  // elu
      st_out(&outp[(size_t)i * ldo + hoff + c], s);
    }
  } else {
    const float inv = 1.0f / (float)NN;
    for (int c = t; c < h; c += 256) {
      float s = cs[hoff + c] * inv;
      s = s > 0.f ? s : (expf(s) - 1.0f);
      st_out(&outp[(size_t)i * ldo + hoff + c], s);
    }
  }
}

// precompute normalized attention weights: att_c[i][hd][k] (k < deg[i]).
// grid (NN, NH/4), block 256 = 4 waves; wave w -> head by*4+w.
__global__ __launch_bounds__(256)
void att_pre(const float* __restrict__ f1, const float* __restrict__ f2,
             const int* __restrict__ nbr, const int* __restrict__ deg,
             float* __restrict__ att_c) {
  __shared__ int   nb_sh[CAP];
  __shared__ float att_sh[4][CAP];
  int i = blockIdx.x;
  int t = threadIdx.x, w = t >> 6, lane = t & 63;
  int hd = blockIdx.y * 4 + w;
  int d = deg[i];
  if (d == 0) return;   // uniform across block: safe before syncthreads
  for (int k = t; k < d; k += 256) nb_sh[k] = nbr[(size_t)i * CAP + k];
  __syncthreads();
  float fi = f1[(size_t)hd * NN + i];
  const float* F2 = f2 + (size_t)hd * NN;
  float lmax = -INFINITY;
  for (int k = lane; k < d; k += 64) {
    float e = fi + F2[nb_sh[k]];
    e = e > 0.f ? e : 0.02f * e;   // leaky_relu slope 0.02
    att_sh[w][k] = e;
    lmax = fmaxf(lmax, e);
  }
  for (int off = 32; off; off >>= 1) lmax = fmaxf(lmax, __shfl_xor(lmax, off));
  float ls = 0.f;
  for (int k = lane; k < d; k += 64) {
    float p = expf(att_sh[w][k] - lmax);
    att_sh[w][k] = p; ls += p;
  }
  for (int off = 32; off; off >>= 1) ls += __shfl_xor(ls, off);
  float inv = 1.0f / ls;
  float* ao = att_c + ((size_t)i * NH + hd) * CAP;
  for (int k = lane; k < d; k += 64) ao[k] = att_sh[w][k] * inv;
}

// column-chunked PV gather + elu. grid (PVC, NN/PVR) — chunk is the FAST grid dim
// so all blocks of chunk c land on XCD c%8 (gridDim.x=16 multiple of 8).
__global__ __launch_bounds__(256)
void spmm_pv(const unsigned short* __restrict__ Whb,   // [NN][HCAT] bf16
             const float* __restrict__ att_c,          // [NN][NH][CAP]
             const int* __restrict__ nbr, const int* __restrict__ deg,
             const float* __restrict__ cs,
             unsigned short* __restrict__ outp) {      // [NN][HCAT] bf16
  __shared__ int nb_sh[PVR][CAP];
  __shared__ int d_sh[PVR];
  int t = threadIdx.x;
  int r0 = blockIdx.y * PVR;
  int u0 = blockIdx.x * PVU;
  int nu = (u0 + PVU <= HCAT / 8) ? PVU : (HCAT / 8 - u0);
  if (t < PVR) d_sh[t] = deg[r0 + t];
  for (int q = t; q < PVR * CAP; q += 256) {
    int r = q / CAP, k = q - r * CAP;
    nb_sh[r][k] = nbr[(size_t)(r0 + r) * CAP + k];
  }
  __syncthreads();
  const float invn = 1.0f / (float)NN;
  int total = PVR * nu;
  for (int q = t; q < total; q += 256) {
    int r = q / nu, u = q - r * nu;
    int i = r0 + r;
    int gu = u0 + u;                       // global short8 unit
    int hd = gu / (HHID / 8);              // 75 units per head
    int d = d_sh[r];
    const unsigned short* base = Whb + (size_t)gu * 8;
    unsigned short o8[8];
    if (d > 0) {
      const float* av = att_c + ((size_t)i * NH + hd) * CAP;
      float a8[8] = {};
      for (int k = 0; k < d; k++) {
        float a = av[k];
        short8 v = *(const short8*)(base + (size_t)nb_sh[r][k] * HCAT);
#pragma unroll
        for (int j = 0; j < 8; j++) a8[j] += a * bf2f((unsigned short)v[j]);
      }
#pragma unroll
      for (int j = 0; j < 8; j++) {
        float s = a8[j];
        s = s > 0.f ? s : (expf(s) - 1.0f);   // elu
        o8[j] = f2bf(s);
      }
    } else {
#pragma unroll
      for (int j = 0; j < 8; j++) {
        float s = cs[(size_t)gu * 8 + j] * invn;
        s = s > 0.f ? s : (expf(s) - 1.0f);
        o8[j] = f2bf(s);
      }
    }
    *(short8*)(outp + (size_t)i * HCAT + (size_t)gu * 8) = *(const short8*)o8;
  }
}

// out layer, bf16 in / fp32 out: grid (NN), block 128; 125 short8 chunks of DOUT=1000
__global__ __launch_bounds__(128)
void spmm_att_o(const unsigned short* __restrict__ Wh,   // [NN][DOUT] bf16
                const float* __restrict__ f1, const float* __restrict__ f2,
                const int* __restrict__ nbr, const int* __restrict__ deg,
                const float* __restrict__ cs,
                float* __restrict__ outp) {              // [NN][DOUT] fp32
  __shared__ int   nb_sh[CAP];
  __shared__ float att_sh[CAP];
  __shared__ float red[128];
  int i = blockIdx.x, t = threadIdx.x;
  int d = deg[i];
  if (d > 0) {
    float fi = f1[i];
    float lmax = -INFINITY;
    for (int k = t; k < d; k += 128) {
      int j = nbr[(size_t)i * CAP + k];
      nb_sh[k] = j;
      float e = fi + f2[j];
      e = e > 0.f ? e : 0.02f * e;
      att_sh[k] = e;
      lmax = fmaxf(lmax, e);
    }
    red[t] = lmax; __syncthreads();
    for (int s = 64; s; s >>= 1) { if (t < s) red[t] = fmaxf(red[t], red[t + s]); __syncthreads(); }
    float m = red[0]; __syncthreads();
    float ls = 0.f;
    for (int k = t; k < d; k += 128) { float p = expf(att_sh[k] - m); att_sh[k] = p; ls += p; }
    red[t] = ls; __syncthreads();
    for (int s = 64; s; s >>= 1) { if (t < s) red[t] += red[t + s]; __syncthreads(); }
    float inv = 1.0f / red[0]; __syncthreads();
    for (int k = t; k < d; k += 128) att_sh[k] *= inv;
    __syncthreads();
    for (int cc = t; cc < DOUT / 8; cc += 128) {
      float a8[8] = {};
      const unsigned short* base = Wh + (size_t)cc * 8;
      for (int k = 0; k < d; k++) {
        float av = att_sh[k];
        short8 v = *(const short8*)(base + (size_t)nb_sh[k] * DOUT);
#pragma unroll
      for (int j = 0; j < 8; j++)
          a8[j] += av * bf2f((unsigned short)v[j]);
      }
      float o[8];
#pragma unroll
      for (int j = 0; j < 8; j++) {
        float s = a8[j];
        o[j] = s > 0.f ? s : (expf(s) - 1.0f);
      }
      *(float4*)(outp + (size_t)i * DOUT + (size_t)cc * 8)     = make_float4(o[0], o[1], o[2], o[3]);
      *(float4*)(outp + (size_t)i * DOUT + (size_t)cc * 8 + 4) = make_float4(o[4], o[5], o[6], o[7]);
    }
  } else {
    const float invn = 1.0f / (float)NN;
    for (int c = t; c < DOUT; c += 128) {
      float s = cs[c] * invn;
      outp[(size_t)i * DOUT + c] = s > 0.f ? s : (expf(s) - 1.0f);
    }
  }
}

// ---------------- bf16 conversion kernels ----------------

// x [NN][FF] fp32 -> xb [NN][FP] bf16 (zero-padded K)
__global__ void conv_x_bf16(const float* __restrict__ x, unsigned short* __restrict__ xb) {
  int i = blockIdx.x, t = threadIdx.x;   // FP=320 threads
  float v = (t < FF) ? x[(size_t)i * FF + t] : 0.0f;
  xb[(size_t)i * FP + t] = f2bf(v);
}

// W [K][N] fp32 (z-batched, stride wz) -> Wt [Npad][ldt] bf16, Wt[n][k] = W[k][n], 0-pad.
__global__ void convT_gen(const float* __restrict__ W, unsigned short* __restrict__ Wt,
                          int K, int N, int ldw, long wz, int ldt, long tz) {
  __shared__ float tile[32][33];
  const float* Wp = W + (size_t)blockIdx.z * wz;
  unsigned short* Tp = Wt + (size_t)blockIdx.z * tz;
  int k0 = blockIdx.x * 32, n0 = blockIdx.y * 32;
  int tx = threadIdx.x, ty = threadIdx.y;
#pragma unroll
  for (int r = ty; r < 32; r += 8) {
    int kk = k0 + r, n = n0 + tx;
    tile[r][tx] = (kk < K && n < N) ? Wp[(size_t)kk * ldw + n] : 0.0f;
  }
  __syncthreads();
#pragma unroll
  for (int r = ty; r < 32; r += 8) {
    Tp[(size_t)(n0 + r) * ldt + k0 + tx] = f2bf(tile[tx][r]);
  }
}

// fp32 -> bf16 flat copy
__global__ void conv_f2b(const float* __restrict__ in, unsigned short* __restrict__ out, int n) {
  int i = blockIdx.x * blockDim.x + threadIdx.x;
  int stride = gridDim.x * blockDim.x;
  for (; i < n; i += stride) out[i] = f2bf(in[i]);
}

// ---------------- bf16 MFMA GEMM ----------------
// C = A @ Bt^T. BM=BN=128, BK=32, 256 thr = 4 waves (2x2), wave tile 64x64,
// mfma 16x16x32 bf16, global_load_lds(16B) staging. OT = float or ushort (bf16 C).
// SWZ=1: XCD-chunked block swizzle (requires nwg % 8 == 0).
// C base: z < zsplit -> C0 + z*cz; else C1 + (z-zsplit)*cz (split-K partial buffers).
template <int LDA, int LDB, int LDC, int NREAL, int KCHUNK, int KTOT, int SWZ, typename OT>
__global__ __launch_bounds__(256)
void gemm_bf16_t(const unsigned short* __restrict__ A, long az,
                 const unsigned short* __restrict__ Bt, long bz,
                 OT* __restrict__ C0, OT* __restrict__ C1, int zsplit, long cz) {
  __shared__ __align__(16) unsigned short As[128 * 32];  // [row][k] 8 KB
  __shared__ __align__(16) unsigned short Bs[128 * 32];  // [col][k] 8 KB
  int bx = blockIdx.x, by = blockIdx.y, bz_ = blockIdx.z;
  if (SWZ) {
    int gx = gridDim.x, gy = gridDim.y;
    int nwg = gx * gy * gridDim.z;
    int lin = bx + gx * (by + gy * bz_);
    int q = nwg >> 3;
    int lin2 = (lin & 7) * q + (lin >> 3);   // XCD-chunked, bijective (nwg%8==0)
    bx = lin2 % gx; by = (lin2 / gx) % gy; bz_ = lin2 / (gx * gy);
  }
  const int z = bz_;
  A  += (size_t)z * az;
  Bt += (size_t)z * bz;
  OT* C = (z < zsplit) ? (C0 + (size_t)z * cz) : (C1 + (size_t)(z - zsplit) * cz);
  int ks, ke;
  if (KCHUNK > 0) {
    ks = z * KCHUNK;
    ke = (ks + KCHUNK < KTOT) ? (ks + KCHUNK) : KTOT;
  } else {
    ks = 0; ke = KTOT;
  }
  const int t = threadIdx.x;
  const int w = t >> 6, lane = t & 63;
  const int m0 = by * 128, n0 = bx * 128;
  const int c0 = t, c1 = t + 256;
  const int ra0 = c0 >> 2, ca0 = (c0 & 3) * 8;
  const int ra1 = c1 >> 2, ca1 = (c1 & 3) * 8;
  const unsigned short* gA0 = A + (size_t)(m0 + ra0) * LDA + ca0;
  const unsigned short* gA1 = A + (size_t)(m0 + ra1) * LDA + ca1;
  const unsigned short* gB0 = Bt + (size_t)(n0 + ra0) * LDB + ca0;
  const unsigned short* gB1 = Bt + (size_t)(n0 + ra1) * LDB + ca1;
  unsigned short* lA0 = As + (size_t)w * 512;
  unsigned short* lA1 = As + (size_t)(4 + w) * 512;
  unsigned short* lB0 = Bs + (size_t)w * 512;
  unsigned short* lB1 = Bs + (size_t)(4 + w) * 512;
  const int wm = (w >> 1) * 64, wn = (w & 1) * 64;
  const int arow = lane & 15, acol = (lane >> 4) * 8;
  f32x4 acc[4][4] = {};
  for (int k = ks; k < ke; k += 32) {
    __builtin_amdgcn_global_load_lds((const __attribute__((address_space(1))) void*)(gA0 + k),
                                     (__attribute__((address_space(3))) void*)(lA0), 16, 0, 0);
    __builtin_amdgcn_global_load_lds((const __attribute__((address_space(1))) void*)(gA1 + k),
                                     (__attribute__((address_space(3))) void*)(lA1), 16, 0, 0);
    __builtin_amdgcn_global_load_lds((const __attribute__((address_space(1))) void*)(gB0 + k),
                                     (__attribute__((address_space(3))) void*)(lB0), 16, 0, 0);
    __builtin_amdgcn_global_load_lds((const __attribute__((address_space(1))) void*)(gB1 + k),
                                     (__attribute__((address_space(3))) void*)(lB1), 16, 0, 0);
    __syncthreads();
    short8 a[4], b[4];
#pragma unroll
    for (int i = 0; i < 4; i++)
      a[i] = *(const short8*)&As[(wm + i * 16 + arow) * 32 + acol];
#pragma unroll
    for (int j = 0; j < 4; j++)
      b[j] = *(const short8*)&Bs[(wn + j * 16 + arow) * 32 + acol];
#pragma unroll
    for (int i = 0; i < 4; i++)
#pragma unroll
      for (int j = 0; j < 4; j++)
        acc[i][j] = __builtin_amdgcn_mfma_f32_16x16x32_bf16(a[i], b[j], acc[i][j], 0, 0, 0);
    __syncthreads();
  }
  // C/D layout (m89-verified): col = lane&15, row = (lane>>4)*4 + reg
  const int crow = (lane >> 4) * 4, ccol = lane & 15;
#pragma unroll
  for (int i = 0; i < 4; i++)
#pragma unroll
    for (int j = 0; j < 4; j++) {
      int gc = n0 + wn + j * 16 + ccol;
      if (gc < NREAL) {
#pragma unroll
        for (int r = 0; r < 4; r++)
          st_out(&C[(size_t)(m0 + wm + i * 16 + crow + r) * LDC + gc], acc[i][j][r]);
      }
    }
}

// sum KSPL split-K partials (KSP0 in p0, rest in p1) -> bf16 accb
__global__ void addn_kernel(const float* __restrict__ p0, const float* __restrict__ p1,
                            unsigned short* __restrict__ ob) {
  const int n = NN * DOUT;
  int i = blockIdx.x * blockDim.x + threadIdx.x;
  int stride = gridDim.x * blockDim.x;
  for (; i < n; i += stride) {
    float v = 0.f;
#pragma unroll
    for (int z = 0; z < KSP0; z++) v += p0[(size_t)z * n + i];
#pragma unroll
    for (int z = 0; z < KSPL - KSP0; z++) v += p1[(size_t)z * n + i];
    ob[i] = f2bf(v);
  }
}

// ---------------- thin-M fp32 GEMM (MLP head: M=128) ----------------
template <int K, int KS>
__global__ __launch_bounds__(256)
void gemm_thin(const float* __restrict__ A, const float* __restrict__ B,
               float* __restrict__ P, int N) {
  constexpr int KC = K / KS;            // 125 for K=1000, KS=8
  __shared__ float Ash[128][KC + 3];
  int t = threadIdx.x;
  int tx = t & 63, ty = t >> 6;
  int n0 = blockIdx.x * 64, kz = blockIdx.y;
  int ks = kz * KC;
  for (int idx = t; idx < 128 * KC; idx += 256) {
    int r = idx / KC, c = idx - r * KC;
    Ash[r][c] = A[(size_t)r * K + ks + c];
  }
  __syncthreads();
  int nn = n0 + tx; if (nn > N - 1) nn = N - 1;   // clamp B loads (write guarded)
  const float* Bp = B + (size_t)ks * N + nn;
  int m0 = ty * 32;
  float acc[32] = {};
  for (int k4 = 0; k4 < KC / 4; k4++) {
    int k = k4 * 4;
    float w0 = Bp[(size_t)(k + 0) * N];
    float w1 = Bp[(size_t)(k + 1) * N];
    float w2 = Bp[(size_t)(k + 2) * N];
    float w3 = Bp[(size_t)(k + 3) * N];
#pragma unroll
    for (int mm = 0; mm < 32; mm++) {
      float4 a = *(const float4*)&Ash[m0 + mm][k];
      acc[mm] += a.x * w0 + a.y * w1 + a.z * w2 + a.w * w3;
    }
  }
#pragma unroll
  for (int k = (KC / 4) * 4; k < KC; k++) {
    float w0 = Bp[(size_t)k * N];
#pragma unroll
    for (int mm = 0; mm < 32; mm++) acc[mm] += Ash[m0 + mm][k] * w0;
  }
  if (n0 + tx < N) {
    float* Pp = P + (size_t)kz * 128 * N;
#pragma unroll
    for (int mm = 0; mm < 32; mm++)
      Pp[(size_t)(m0 + mm) * N + n0 + tx] = acc[mm];
  }
}

// reduce KS partials + bias (+relu if EPI==2)
template <int N, int KS, int EPI>
__global__ void thin_reduce(const float* __restrict__ P, const float* __restrict__ bias,
                            float* __restrict__ C) {
  int i = blockIdx.x * blockDim.x + threadIdx.x;
  const int total = 128 * N;
  if (i >= total) return;
  int n = i % N;
  float v = 0.f;
#pragma unroll
  for (int z = 0; z < KS; z++) v += P[(size_t)z * total + i];
  v += bias[n];
  if (EPI == 2) v = v > 0.f ? v : 0.f;
  C[i] = v;
}

// ---------------- tiled fp32 GEMM (fallback path only) ----------------
template <int BM_, int BN_, int EPI>
__global__ __launch_bounds__(256)
void gemm_t(const float* __restrict__ A, const float* __restrict__ B,
            float* __restrict__ C, const float* __restrict__ bias,
            int M, int N, int K, int lda, int ldb, int ldc, int accum,
            long bz, long cz) {
  constexpr int MR = BM_ / 16, NR = BN_ / 16;
  __shared__ float As[16][BM_ + 4];
  __shared__ float Bs[16][BN_ + 4];
  const float* Bp = B + (size_t)blockIdx.z * bz;
  float* Cp = C + (size_t)blockIdx.z * cz;
  int tx = threadIdx.x, ty = threadIdx.y;
  int tid = ty * 16 + tx;
  int m0 = blockIdx.y * BM_, n0 = blockIdx.x * BN_;
  float acc[MR][NR] = {};
  for (int k0 = 0; k0 < K; k0 += 16) {
#pragma unroll
    for (int p = 0; p < BM_ / 64; p++) {
      int id = tid + p * 256;
      int r = id >> 2, c4 = (id & 3) * 4;
      int gm = m0 + r;
      float v[4];
      if (gm < M && k0 + c4 + 3 < K) {
        const float4 t4 = *(const float4*)&A[(size_t)gm * lda + k0 + c4];
        v[0] = t4.x; v[1] = t4.y; v[2] = t4.z; v[3] = t4.w;
      } else {
#pragma unroll
        for (int q = 0; q < 4; q++) {
          int gk = k0 + c4 + q;
          v[q] = (gm < M && gk < K) ? A[(size_t)gm * lda + gk] : 0.0f;
        }
      }
#pragma unroll
      for (int q = 0; q < 4; q++) As[c4 + q][r] = v[q];
    }
#pragma unroll
    for (int p = 0; p < BN_ / 64; p++) {
      int id = tid + p * 256;
      int r = id / (BN_ / 4), c4 = (id % (BN_ / 4)) * 4;
      int gk = k0 + r, gn = n0 + c4;
      float v[4];
      if (gk < K && gn + 3 < N) {
        const float4 t4 = *(const float4*)&Bp[(size_t)gk * ldb + gn];
        v[0] = t4.x; v[1] = t4.y; v[2] = t4.z; v[3] = t4.w;
      } else {
#pragma unroll
        for (int q = 0; q < 4; q++)
          v[q] = (gk < K && gn + q < N) ? Bp[(size_t)gk * ldb + gn + q] : 0.0f;
      }
      *(float4*)&Bs[r][c4] = *(const float4*)v;
    }
    __syncthreads();
#pragma unroll
    for (int kk = 0; kk < 16; kk++) {
      float a[MR], b[NR];
#pragma unroll
      for (int q = 0; q < MR / 4; q++)
        *(float4*)&a[q * 4] = *(const float4*)&As[kk][ty * MR + q * 4];
#pragma unroll
      for (int q = 0; q < NR / 4; q++)
        *(float4*)&b[q * 4] = *(const float4*)&Bs[kk][tx * NR + q * 4];
#pragma unroll
      for (int i = 0; i < MR; i++)
#pragma unroll
        for (int j = 0; j < NR; j++) acc[i][j] += a[i] * b[j];
    }
    __syncthreads();
  }
#pragma unroll
  for (int i = 0; i < MR; i++) {
    int gm = m0 + ty * MR + i;
    if (gm >= M) continue;
#pragma unroll
    for (int j = 0; j < NR; j++) {
      int gn = n0 + tx * NR + j;
      if (gn >= N) continue;
      float r = acc[i][j];
      if (accum) r += Cp[(size_t)gm * ldc + gn];
      if (EPI == 2) { r += bias[gn]; r = r > 0.f ? r : 0.f; }
      else if (EPI == 3) { r += bias[gn]; }
      Cp[(size_t)gm * ldc + gn] = r;
    }
  }
}

// ---------------- pooling ----------------

__global__ void pool_prep(const int* __restrict__ batch, int* __restrict__ startg, int* __restrict__ cntg) {
  int n = blockIdx.x * blockDim.x + threadIdx.x;
  if (n >= NN) return;
  int b = batch[n];
  if (n == 0 || batch[n - 1] != b) startg[b] = n;
  atomicAdd(&cntg[b], 1);
}

__global__ void pool_kernel(const float* __restrict__ outb,
                            const int* __restrict__ startg, const int* __restrict__ cntg,
                            float* __restrict__ pooled) {
  int g = blockIdx.x, t = threadIdx.x;
  int st = startg[g], c = cntg[g];
  for (int ch = t; ch < DOUT; ch += 256) {
    float s = 0.f;
    for (int k = 0; k < c; k++) s += outb[(size_t)(st + k) * DOUT + ch];
    pooled[(size_t)g * DOUT + ch] = s / (float)(c > 0 ? c : 1);
  }
}

// ---------------- launch ----------------

static inline int cdiv(int a, int b) { return (a + b - 1) / b; }

extern "C" void kernel_launch(void* const* d_in, const int* in_sizes, int n_in,
                              void* d_out, int out_size, void* d_ws, size_t ws_size,
                              hipStream_t stream) {
  const float* x        = (const float*)d_in[0];
  const int*   ei       = (const int*)d_in[1];
  const int*   batch    = (const int*)d_in[2];
  const float* W_heads  = (const float*)d_in[3];
  const float* a1_heads = (const float*)d_in[4];
  const float* a2_heads = (const float*)d_in[5];
  const float* W_out    = (const float*)d_in[6];
  const float* a1_out   = (const float*)d_in[7];
  const float* a2_out   = (const float*)d_in[8];
  const float* W1       = (const float*)d_in[9];
  const float* b1       = (const float*)d_in[10];
  const float* W2       = (const float*)d_in[11];
  const float* b2       = (const float*)d_in[12];
  float* outd = (float*)d_out;
  (void)in_sizes; (void)n_in; (void)out_size;

  char* w = (char*)d_ws;
  size_t off = 0;
  auto alloc = [&](size_t bytes) {
    void* p = w + off;
    off += (bytes + 255) & ~(size_t)255;
    return p;
  };
  auto al = [](size_t b) { return (b + 255) & ~(size_t)255; };

  // common small buffers
  unsigned char* mask = (unsigned char*)alloc((size_t)NN * NN);      // 4 MB
  int*   nbr    = (int*)alloc((size_t)NN * CAP * 4);                 // 1.3 MB
  int*   deg    = (int*)alloc((size_t)NN * 4);
  float* acc    = (float*)alloc((size_t)NN * DOUT * 4);              // 8.2 MB (fallback + MLP partials)
  unsigned short* accb = (unsigned short*)alloc((size_t)NN * DOUT * 2); // 4.1 MB
  float* outb   = (float*)alloc((size_t)NN * DOUT * 4);              // 8.2 MB
  float* f1o    = (float*)alloc((size_t)NN * 4);
  float* f2o    = (float*)alloc((size_t)NN * 4);
  float* cso    = (float*)alloc((size_t)DOUT * 4);
  float* pooled = (float*)alloc((size_t)NG * DOUT * 4);
  float* hid    = (float*)alloc((size_t)NG * MLPD * 4);
  int*   startg = (int*)alloc((size_t)NG * 4);
  int*   cntg   = (int*)alloc((size_t)NG * 4);
  size_t off_common = off;

  // batched-path big buffers
  size_t need_batched = off_common
      + al((size_t)NN * HCAT * 2)           // Whb (bf16) / split-K partials
      + al((size_t)NN * HCAT * 2)           // hcat bf16
      + al((size_t)NPAD * HCAT * 2)         // W_out^T bf16 (padded)
      + al((size_t)NN * FP * 2)             // x bf16
      + al((size_t)NH * HP * FP * 2)        // W_heads^T bf16
      + al((size_t)NN * NH * CAP * 4)       // att_c
      + al((size_t)NH * NN * 4) * 2         // f1_all + f2_all
      + al((size_t)NH * HHID * 4)           // cs_all
      + al((size_t)NH * FF * 4) * 2         // w1b + w2b
      + al((size_t)FF * 4);                 // xsum
  bool batched = ws_size >= need_batched;

  // 1) adjacency mask + CSR (dedupes duplicate edges like .at[].set(1.0))
  zero_words<<<4096, 256, 0, stream>>>((unsigned int*)mask, NN * NN / 4);
  scatter_mask<<<cdiv(NE, 256), 256, 0, stream>>>(ei, mask);
  build_csr<<<NN / 4, 256, 0, stream>>>(mask, nbr, deg);

  if (batched) {
    unsigned short* Whb   = (unsigned short*)alloc((size_t)NN * HCAT * 2);  // 49.2 MB
    unsigned short* hcatb = (unsigned short*)alloc((size_t)NN * HCAT * 2);  // 49.2 MB
    unsigned short* Wt    = (unsigned short*)alloc((size_t)NPAD * HCAT * 2);// 24.6 MB
    unsigned short* xb    = (unsigned short*)alloc((size_t)NN * FP * 2);    // 1.3 MB
    unsigned short* Wth   = (unsigned short*)alloc((size_t)NH * HP * FP * 2);// 8.2 MB
    float* att_c  = (float*)alloc((size_t)NN * NH * CAP * 4);               // 26.2 MB
    float* f1a    = (float*)alloc((size_t)NH * NN * 4);
    float* f2a    = (float*)alloc((size_t)NH * NN * 4);
    float* csa    = (float*)alloc((size_t)NH * HHID * 4);
    float* w1b    = (float*)alloc((size_t)NH * FF * 4);
    float* w2b    = (float*)alloc((size_t)NH * FF * 4);
    float* xsum   = (float*)alloc((size_t)FF * 4);
    // split-K partials: all 6 z-slices in Whb (6*8.19 = 49.15 <= 49.2 MB, dead after spmm_pv)
    float* partC0 = (float*)Whb;
    float* partC1 = att_c;   // unused at KSP0 == KSPL (kept for signature)

    // 2) Whb[:, hd*600:+600] = bf16(x @ W_heads[hd]) via MFMA, one launch z=heads
    conv_x_bf16<<<NN, FP, 0, stream>>>(x, xb);
    convT_gen<<<dim3(FP / 32, HP / 32, NH), dim3(32, 8), 0, stream>>>(
        W_heads, Wth, FF, HHID, HHID, (long)FF * HHID, FP, (long)HP * FP);
    gemm_bf16_t<FP, FP, HCAT, HHID, 0, FP, 1, unsigned short>
        <<<dim3(HP / 128, NN / 128, NH), 256, 0, stream>>>(
        xb, 0L, Wth, (long)HP * FP, Whb, Whb, NH, (long)HHID);
    // 3) attention logits via associativity (fp32, no Whb pass):
    //    f1 = x@(W@a1); csa = colsum(x)@W
    w12_kernel<<<dim3(FF, NH), 64, 0, stream>>>(W_heads, a1_heads, a2_heads, w1b, w2b);
    f12x_kernel<<<NN, 256, 0, stream>>>(x, w1b, w2b, f1a, f2a);
    zero_words<<<1, 256, 0, stream>>>((unsigned int*)xsum, FF);
    colsum_at_f32<<<dim3(cdiv(FF, 256), NN / 64), 256, 0, stream>>>(x, FF, FF, xsum);
    zero_words<<<12, 256, 0, stream>>>((unsigned int*)csa, NH * HHID);
    csa_at<<<dim3(cdiv(HHID, 256), NH, 5), 256, 0, stream>>>(xsum, W_heads, csa);
    // 3b) W_out -> bf16 transposed (B^T layout for contiguous MFMA B-frags)
    convT_gen<<<dim3(HCAT / 32, NPAD / 32, 1), dim3(32, 8), 0, stream>>>(
        W_out, Wt, HCAT, DOUT, DOUT, 0L, HCAT, 0L);
    // 4) softmax precompute + column-chunked PV gather (chunk->XCD L2 pin)
    att_pre<<<dim3(NN, NH / 4), 256, 0, stream>>>(f1a, f2a, nbr, deg, att_c);
    spmm_pv<<<dim3(PVC, NN / PVR), 256, 0, stream>>>(Whb, att_c, nbr, deg, csa, hcatb);
    // 5) acc = hcat @ W_out via bf16 MFMA, split-K=6 (768 blocks, XCD swizzle)
    gemm_bf16_t<HCAT, HCAT, DOUT, DOUT, KCH, HCAT, 1, float>
        <<<dim3(NPAD / 128, NN / 128, KSPL), 256, 0, stream>>>(
        hcatb, 0L, Wt, 0L, partC0, partC1, KSP0, (long)NN * DOUT);
    addn_kernel<<<2048, 256, 0, stream>>>(partC0, partC1, accb);
    // 6) output attention layer (all-bf16 inputs)
    f12_bf16<<<dim3(NN, 1), 64, 0, stream>>>(accb, DOUT, DOUT, a1_out, a2_out, 0, f1o, f2o);
    zero_words<<<1, 256, 0, stream>>>((unsigned int*)cso, DOUT);
    colsum_at_bf16<<<dim3(cdiv(DOUT, 256), NN / 64), 256, 0, stream>>>(accb, DOUT, DOUT, cso);
    spmm_att_o<<<dim3(NN), 128, 0, stream>>>(accb, f1o, f2o, nbr, deg, cso, outb);
  } else {
    // fallback: per-head pipeline (fp32 GEMM + fp32 spmm)
    float* Wh   = (float*)alloc((size_t)NN * HHID * 4);
    float* hout = (float*)alloc((size_t)NN * HHID * 4);
    float* f1   = (float*)alloc((size_t)NN * 4);
    float* f2   = (float*)alloc((size_t)NN * 4);
    float* cs   = (float*)alloc((size_t)HHID * 4);
    zero_words<<<8000, 256, 0, stream>>>((unsigned int*)acc, NN * DOUT);
    for (int hd = 0; hd < NH; hd++) {
      gemm_t<64, 64, 0><<<dim3(cdiv(HHID, 64), cdiv(NN, 64), 1), dim3(16, 16), 0, stream>>>(
          x, W_heads + (size_t)hd * FF * HHID, Wh, nullptr,
          NN, HHID, FF, FF, HHID, HHID, 0, 0L, 0L);
      f12_kernel<<<dim3(NN, 1), 64, 0, stream>>>(Wh, HHID, HHID,
          a1_heads + (size_t)hd * HHID, a2_heads + (size_t)hd * HHID, 0, f1, f2);
      colsum_kernel<<<dim3(cdiv(HHID, 256), 1), 256, 0, stream>>>(Wh, HHID, HHID, cs);
      spmm_att<float><<<dim3(NN, 1), 256, 0, stream>>>(Wh, HHID, HHID, f1, f2,
                                                       nbr, deg, cs, hout, HHID);
      gemm_t<64, 64, 0><<<dim3(cdiv(DOUT, 64), cdiv(NN, 64), 1), dim3(16, 16), 0, stream>>>(
          hout, W_out + (size_t)hd * HHID * DOUT, acc, nullptr,
          NN, DOUT, HHID, HHID, DOUT, DOUT, 1, 0L, 0L);
    }
    conv_f2b<<<2048, 256, 0, stream>>>(acc, accb, NN * DOUT);
    // 6) output attention layer (fp32 logits from acc)
    f12_kernel<<<dim3(NN, 1), 64, 0, stream>>>(acc, DOUT, DOUT, a1_out, a2_out, 0, f1o, f2o);
    zero_words<<<1, 256, 0, stream>>>((unsigned int*)cso, DOUT);
    colsum_at_f32<<<dim3(cdiv(DOUT, 256), NN / 64), 256, 0, stream>>>(acc, DOUT, DOUT, cso);
    spmm_att_o<<<dim3(NN), 128, 0, stream>>>(accb, f1o, f2o, nbr, deg, cso, outb);
  }

  // 7) global mean pool (batch is sorted)
  zero_words<<<1, 256, 0, stream>>>((unsigned int*)startg, NG * 2);  // startg+cntg contiguous
  pool_prep<<<NN / 256, 256, 0, stream>>>(batch, startg, cntg);
  pool_kernel<<<NG, 256, 0, stream>>>(outb, startg, cntg, pooled);

  // 8) MLP head — thin-M split-K GEMMs (acc is dead here in both paths; reuse for partials)
  float* mlpP = acc;   // 8*128*1000*4 = 4.1 MB <= 8.2 MB
  gemm_thin<DOUT, 8><<<dim3(cdiv(MLPD, 64), 8), 256, 0, stream>>>(pooled, W1, mlpP, MLPD);
  thin_reduce<MLPD, 8, 2><<<cdiv(NG * MLPD, 256), 256, 0, stream>>>(mlpP, b1, hid);
  gemm_thin<MLPD, 8><<<dim3(cdiv(NOUTD, 64), 8), 256, 0, stream>>>(hid, W2, mlpP, NOUTD);
  thin_reduce<NOUTD, 8, 3><<<cdiv(NG * NOUTD, 256), 256, 0, stream>>>(mlpP, b2, outd);
}

// Round 11
// 377.681 us; speedup vs baseline: 1.0837x; 1.0441x over previous
//
#include <hip/hip_runtime.h>
#include <math.h>

// Problem constants (from setup_inputs)
#define NN   2048   // nodes
#define FF   300    // input features
#define FP   320    // FF padded to 32 multiple for MFMA K
#define NH   20     // heads
#define HHID 600    // per-head hidden
#define HP   640    // HHID padded to 128 multiple for MFMA N
#define HCAT (NH * HHID)  // 12000
#define DOUT 1000   // out_att width
#define NPAD 1024   // DOUT padded to 128 multiple for MFMA GEMM
#define MLPD 1000   // MLP hidden
#define NOUTD 768   // final output
#define NE   32768  // edges
#define NG   128    // graphs
#define CAP  160    // max neighbors kept per row (Poisson(16) tail safe)
#define KSPL 6      // split-K for K=12000 GEMM (768 blocks = 3/CU; 8 regressed, r8)
#define KCH  2016   // K chunk (x32); last chunk = 12000-5*2016 = 1920
#define PVC  16     // PV column chunks (gridDim.x -> XCD pin = chunk%8)
#define PVR  8      // PV rows per block (r6 champion value; 16 was a regression suspect)
#define PVU  94     // short8-units per PV chunk (1500 total; last chunk = 90)

typedef __attribute__((ext_vector_type(8))) short short8;   // 8 bf16 (A/B frag)
typedef __attribute__((ext_vector_type(4))) float f32x4;    // C/D frag

__device__ __forceinline__ unsigned short f2bf(float f) {
  // round-to-nearest-even fp32 -> bf16
  unsigned int u = __float_as_uint(f);
  u += 0x7fffu + ((u >> 16) & 1u);
  return (unsigned short)(u >> 16);
}
__device__ __forceinline__ float bf2f(unsigned short u) {
  return __uint_as_float(((unsigned int)u) << 16);
}
__device__ __forceinline__ void st_out(float* p, float v) { *p = v; }
__device__ __forceinline__ void st_out(unsigned short* p, float v) { *p = f2bf(v); }

// ---------------- utility kernels ----------------

__global__ void zero_words(unsigned int* __restrict__ p, int n) {
  int i = blockIdx.x * blockDim.x + threadIdx.x;
  int stride = gridDim.x * blockDim.x;
  for (; i < n; i += stride) p[i] = 0u;
}

__global__ void scatter_mask(const int* __restrict__ ei, unsigned char* __restrict__ mask) {
  int e = blockIdx.x * blockDim.x + threadIdx.x;
  if (e < NE) {
    int s = ei[e], d = ei[NE + e];
    mask[(size_t)s * NN + d] = 1;
  }
}

// one wave per row: dword-load the adjacency row, ballot-compact per byte lane
__global__ void build_csr(const unsigned char* __restrict__ mask,
                          int* __restrict__ nbr, int* __restrict__ deg) {
  int wave = threadIdx.x >> 6, lane = threadIdx.x & 63;
  int i = blockIdx.x * 4 + wave;
  if (i >= NN) return;
  const unsigned* roww = (const unsigned*)(mask + (size_t)i * NN);
  int cnt = 0;
  for (int c0 = 0; c0 < NN; c0 += 256) {        // 256 bytes per iter
    unsigned word = roww[(c0 >> 2) + lane];
#pragma unroll
    for (int b = 0; b < 4; b++) {
      bool p = ((word >> (8 * b)) & 0xffu) != 0u;
      unsigned long long bal = __ballot(p);
      if (p) {
        int pos = cnt + (int)__popcll(bal & ((1ull << lane) - 1ull));
        if (pos < CAP) nbr[(size_t)i * CAP + pos] = c0 + lane * 4 + b;
      }
      cnt += (int)__popcll(bal);
    }
  }
  if (lane == 0) deg[i] = cnt < CAP ? cnt : CAP;
}

// ---------------- f1/f2 + colsum ----------------

__global__ void f12_kernel(const float* __restrict__ Wh, int ldw, int h,
                           const float* __restrict__ a1, const float* __restrict__ a2,
                           int astride,
                           float* __restrict__ f1, float* __restrict__ f2) {
  int i = blockIdx.x, hd = blockIdx.y;
  int lane = threadIdx.x;
  const float* r = Wh + (size_t)i * ldw + (size_t)hd * h;
  const float* A1 = a1 + (size_t)hd * astride;
  const float* A2 = a2 + (size_t)hd * astride;
  float s1 = 0.f, s2 = 0.f;
  for (int c = lane; c < h; c += 64) {
    float w = r[c];
    s1 += w * A1[c];
    s2 += w * A2[c];
  }
  for (int off = 32; off; off >>= 1) {
    s1 += __shfl_down(s1, off);
    s2 += __shfl_down(s2, off);
  }
  if (lane == 0) { f1[(size_t)hd * NN + i] = s1; f2[(size_t)hd * NN + i] = s2; }
}

// bf16 input, short8-vectorized; h must be divisible by 8
__global__ void f12_bf16(const unsigned short* __restrict__ Wh, int ldw, int h,
                         const float* __restrict__ a1, const float* __restrict__ a2,
                         int astride,
                         float* __restrict__ f1, float* __restrict__ f2) {
  int i = blockIdx.x, hd = blockIdx.y;
  int lane = threadIdx.x;
  const unsigned short* r = Wh + (size_t)i * ldw + (size_t)hd * h;
  const float* A1 = a1 + (size_t)hd * astride;
  const float* A2 = a2 + (size_t)hd * astride;
  float s1 = 0.f, s2 = 0.f;
  for (int c8 = lane; c8 < h / 8; c8 += 64) {
    short8 v = *(const short8*)(r + (size_t)c8 * 8);
#pragma unroll
    for (int j = 0; j < 8; j++) {
      float w = bf2f((unsigned short)v[j]);
      s1 += w * A1[c8 * 8 + j];
      s2 += w * A2[c8 * 8 + j];
    }
  }
  for (int off = 32; off; off >>= 1) {
    s1 += __shfl_down(s1, off);
    s2 += __shfl_down(s2, off);
  }
  if (lane == 0) { f1[(size_t)hd * NN + i] = s1; f2[(size_t)hd * NN + i] = s2; }
}

// serial colsum (fallback path only)
__global__ void colsum_kernel(const float* __restrict__ Wh, int ldw, int h,
                              float* __restrict__ cs) {
  int hd = blockIdx.y;
  int c = blockIdx.x * blockDim.x + threadIdx.x;
  if (c >= h) return;
  size_t off = (size_t)hd * h + c;
  float s = 0.f;
  for (int i = 0; i < NN; i++) s += Wh[(size_t)i * ldw + off];
  cs[(size_t)hd * h + c] = s;
}

// row-parallel colsum + atomics: grid (cdiv(width,256), rows/64); cs pre-zeroed.
__global__ void colsum_at_bf16(const unsigned short* __restrict__ Wh, int ld, int width,
                               float* __restrict__ cs) {
  int c = blockIdx.x * blockDim.x + threadIdx.x;
  if (c >= width) return;
  int r0 = blockIdx.y * 64;
  float s = 0.f;
  for (int i = r0; i < r0 + 64; i++) s += bf2f(Wh[(size_t)i * ld + c]);
  atomicAdd(&cs[c], s);
}

__global__ void colsum_at_f32(const float* __restrict__ Wh, int ld, int width,
                              float* __restrict__ cs) {
  int c = blockIdx.x * blockDim.x + threadIdx.x;
  if (c >= width) return;
  int r0 = blockIdx.y * 64;
  float s = 0.f;
  for (int i = r0; i < r0 + 64; i++) s += Wh[(size_t)i * ld + c];
  atomicAdd(&cs[c], s);
}

// ---------------- sparse attention (softmax + PV + elu) ----------------

// fp32 fallback version: one block (256 thr) per (row, head)
template <typename OT>
__global__ __launch_bounds__(256)
void spmm_att(const float* __restrict__ Wh, int ldw, int h,
              const float* __restrict__ f1, const float* __restrict__ f2,
              const int* __restrict__ nbr, const int* __restrict__ deg,
              const float* __restrict__ cs,
              OT* __restrict__ outp, int ldo) {
  __shared__ float att[CAP];
  __shared__ int   nb[CAP];
  __shared__ float red[256];
  int i = blockIdx.x, hd = blockIdx.y;
  int t = threadIdx.x;
  int d = deg[i];
  size_t hoff = (size_t)hd * h;
  if (d > 0) {
    float fi = f1[(size_t)hd * NN + i];
    const float* F2 = f2 + (size_t)hd * NN;
    float lmax = -INFINITY;
    for (int k = t; k < d; k += 256) {
      int j = nbr[(size_t)i * CAP + k];
      nb[k] = j;
      float e = fi + F2[j];
      e = e > 0.f ? e : 0.02f * e;   // leaky_relu slope 0.02
      att[k] = e;
      lmax = fmaxf(lmax, e);
    }
    red[t] = lmax; __syncthreads();
    for (int s = 128; s; s >>= 1) { if (t < s) red[t] = fmaxf(red[t], red[t + s]); __syncthreads(); }
    float m = red[0]; __syncthreads();
    float ls = 0.f;
    for (int k = t; k < d; k += 256) { float p = expf(att[k] - m); att[k] = p; ls += p; }
    red[t] = ls; __syncthreads();
    for (int s = 128; s; s >>= 1) { if (t < s) red[t] += red[t + s]; __syncthreads(); }
    float inv = 1.0f / red[0]; __syncthreads();
    for (int k = t; k < d; k += 256) att[k] *= inv;
    __syncthreads();
    for (int c = t; c < h; c += 256) {
      float s = 0.f;
      for (int k = 0; k < d; k++) s += att[k] * Wh[(size_t)nb[k] * ldw + hoff + c];
      s = s > 0.f ? s : (expf(s) - 1.0f);  // elu
      st_out(&outp[(size_t)i * ldo + hoff + c], s);
    }
  } else {
    const float inv = 1.0f / (float)NN;
    for (int c = t; c < h; c += 256) {
      float s = cs[hoff + c] * inv;
      s = s > 0.f ? s : (expf(s) - 1.0f);
      st_out(&outp[(size_t)i * ldo + hoff + c], s);
    }
  }
}

// precompute normalized attention weights: att_c[i][hd][k] (k < deg[i]).
// grid (NN, NH/4), block 256 = 4 waves; wave w -> head by*4+w.
__global__ __launch_bounds__(256)
void att_pre(const float* __restrict__ f1, const float* __restrict__ f2,
             const int* __restrict__ nbr, const int* __restrict__ deg,
             float* __restrict__ att_c) {
  __shared__ int   nb_sh[CAP];
  __shared__ float att_sh[4][CAP];
  int i = blockIdx.x;
  int t = threadIdx.x, w = t >> 6, lane = t & 63;
  int hd = blockIdx.y * 4 + w;
  int d = deg[i];
  if (d == 0) return;   // uniform across block: safe before syncthreads
  for (int k = t; k < d; k += 256) nb_sh[k] = nbr[(size_t)i * CAP + k];
  __syncthreads();
  float fi = f1[(size_t)hd * NN + i];
  const float* F2 = f2 + (size_t)hd * NN;
  float lmax = -INFINITY;
  for (int k = lane; k < d; k += 64) {
    float e = fi + F2[nb_sh[k]];
    e = e > 0.f ? e : 0.02f * e;   // leaky_relu slope 0.02
    att_sh[w][k] = e;
    lmax = fmaxf(lmax, e);
  }
  for (int off = 32; off; off >>= 1) lmax = fmaxf(lmax, __shfl_xor(lmax, off));
  float ls = 0.f;
  for (int k = lane; k < d; k += 64) {
    float p = expf(att_sh[w][k] - lmax);
    att_sh[w][k] = p; ls += p;
  }
  for (int off = 32; off; off >>= 1) ls += __shfl_xor(ls, off);
  float inv = 1.0f / ls;
  float* ao = att_c + ((size_t)i * NH + hd) * CAP;
  for (int k = lane; k < d; k += 64) ao[k] = att_sh[w][k] * inv;
}

// column-chunked PV gather + elu. grid (PVC, NN/PVR) — chunk is the FAST grid dim
// so all blocks of chunk c land on XCD c%8 (gridDim.x=16 multiple of 8): each XCD's
// L2 serves a fixed 2048-row x 2-chunk slice (~6 MB) of Whb instead of all 49 MB.
__global__ __launch_bounds__(256)
void spmm_pv(const unsigned short* __restrict__ Whb,   // [NN][HCAT] bf16
             const float* __restrict__ att_c,          // [NN][NH][CAP]
             const int* __restrict__ nbr, const int* __restrict__ deg,
             const float* __restrict__ cs,
             unsigned short* __restrict__ outp) {      // [NN][HCAT] bf16
  __shared__ int nb_sh[PVR][CAP];
  __shared__ int d_sh[PVR];
  int t = threadIdx.x;
  int r0 = blockIdx.y * PVR;
  int u0 = blockIdx.x * PVU;
  int nu = (u0 + PVU <= HCAT / 8) ? PVU : (HCAT / 8 - u0);
  if (t < PVR) d_sh[t] = deg[r0 + t];
  for (int q = t; q < PVR * CAP; q += 256) {
    int r = q / CAP, k = q - r * CAP;
    nb_sh[r][k] = nbr[(size_t)(r0 + r) * CAP + k];
  }
  __syncthreads();
  const float invn = 1.0f / (float)NN;
  int total = PVR * nu;
  for (int q = t; q < total; q += 256) {
    int r = q / nu, u = q - r * nu;
    int i = r0 + r;
    int gu = u0 + u;                       // global short8 unit
    int hd = gu / (HHID / 8);              // 75 units per head
    int d = d_sh[r];
    const unsigned short* base = Whb + (size_t)gu * 8;
    unsigned short o8[8];
    if (d > 0) {
      const float* av = att_c + ((size_t)i * NH + hd) * CAP;
      float a8[8] = {};
      for (int k = 0; k < d; k++) {
        float a = av[k];
        short8 v = *(const short8*)(base + (size_t)nb_sh[r][k] * HCAT);
#pragma unroll
        for (int j = 0; j < 8; j++) a8[j] += a * bf2f((unsigned short)v[j]);
      }
#pragma unroll
      for (int j = 0; j < 8; j++) {
        float s = a8[j];
        s = s > 0.f ? s : (expf(s) - 1.0f);   // elu
        o8[j] = f2bf(s);
      }
    } else {
#pragma unroll
      for (int j = 0; j < 8; j++) {
        float s = cs[(size_t)gu * 8 + j] * invn;
        s = s > 0.f ? s : (expf(s) - 1.0f);
        o8[j] = f2bf(s);
      }
    }
    *(short8*)(outp + (size_t)i * HCAT + (size_t)gu * 8) = *(const short8*)o8;
  }
}

// out layer, bf16 in / fp32 out: grid (NN), block 128; 125 short8 chunks of DOUT=1000
__global__ __launch_bounds__(128)
void spmm_att_o(const unsigned short* __restrict__ Wh,   // [NN][DOUT] bf16
                const float* __restrict__ f1, const float* __restrict__ f2,
                const int* __restrict__ nbr, const int* __restrict__ deg,
                const float* __restrict__ cs,
                float* __restrict__ outp) {              // [NN][DOUT] fp32
  __shared__ int   nb_sh[CAP];
  __shared__ float att_sh[CAP];
  __shared__ float red[128];
  int i = blockIdx.x, t = threadIdx.x;
  int d = deg[i];
  if (d > 0) {
    float fi = f1[i];
    float lmax = -INFINITY;
    for (int k = t; k < d; k += 128) {
      int j = nbr[(size_t)i * CAP + k];
      nb_sh[k] = j;
      float e = fi + f2[j];
      e = e > 0.f ? e : 0.02f * e;
      att_sh[k] = e;
      lmax = fmaxf(lmax, e);
    }
    red[t] = lmax; __syncthreads();
    for (int s = 64; s; s >>= 1) { if (t < s) red[t] = fmaxf(red[t], red[t + s]); __syncthreads(); }
    float m = red[0]; __syncthreads();
    float ls = 0.f;
    for (int k = t; k < d; k += 128) { float p = expf(att_sh[k] - m); att_sh[k] = p; ls += p; }
    red[t] = ls; __syncthreads();
    for (int s = 64; s; s >>= 1) { if (t < s) red[t] += red[t + s]; __syncthreads(); }
    float inv = 1.0f / red[0]; __syncthreads();
    for (int k = t; k < d; k += 128) att_sh[k] *= inv;
    __syncthreads();
    for (int cc = t; cc < DOUT / 8; cc += 128) {
      float a8[8] = {};
      const unsigned short* base = Wh + (size_t)cc * 8;
      for (int k = 0; k < d; k++) {
        float av = att_sh[k];
        short8 v = *(const short8*)(base + (size_t)nb_sh[k] * DOUT);
#pragma unroll
      for (int j = 0; j < 8; j++)
          a8[j] += av * bf2f((unsigned short)v[j]);
      }
      float o[8];
#pragma unroll
      for (int j = 0; j < 8; j++) {
        float s = a8[j];
        o[j] = s > 0.f ? s : (expf(s) - 1.0f);
      }
      *(float4*)(outp + (size_t)i * DOUT + (size_t)cc * 8)     = make_float4(o[0], o[1], o[2], o[3]);
      *(float4*)(outp + (size_t)i * DOUT + (size_t)cc * 8 + 4) = make_float4(o[4], o[5], o[6], o[7]);
    }
  } else {
    const float invn = 1.0f / (float)NN;
    for (int c = t; c < DOUT; c += 128) {
      float s = cs[c] * invn;
      outp[(size_t)i * DOUT + c] = s > 0.f ? s : (expf(s) - 1.0f);
    }
  }
}

// ---------------- bf16 conversion kernels ----------------

// x [NN][FF] fp32 -> xb [NN][FP] bf16 (zero-padded K)
__global__ void conv_x_bf16(const float* __restrict__ x, unsigned short* __restrict__ xb) {
  int i = blockIdx.x, t = threadIdx.x;   // FP=320 threads
  float v = (t < FF) ? x[(size_t)i * FF + t] : 0.0f;
  xb[(size_t)i * FP + t] = f2bf(v);
}

// W [K][N] fp32 (z-batched, stride wz) -> Wt [Npad][ldt] bf16, Wt[n][k] = W[k][n], 0-pad.
__global__ void convT_gen(const float* __restrict__ W, unsigned short* __restrict__ Wt,
                          int K, int N, int ldw, long wz, int ldt, long tz) {
  __shared__ float tile[32][33];
  const float* Wp = W + (size_t)blockIdx.z * wz;
  unsigned short* Tp = Wt + (size_t)blockIdx.z * tz;
  int k0 = blockIdx.x * 32, n0 = blockIdx.y * 32;
  int tx = threadIdx.x, ty = threadIdx.y;
#pragma unroll
  for (int r = ty; r < 32; r += 8) {
    int kk = k0 + r, n = n0 + tx;
    tile[r][tx] = (kk < K && n < N) ? Wp[(size_t)kk * ldw + n] : 0.0f;
  }
  __syncthreads();
#pragma unroll
  for (int r = ty; r < 32; r += 8) {
    Tp[(size_t)(n0 + r) * ldt + k0 + tx] = f2bf(tile[tx][r]);
  }
}

// fp32 -> bf16 flat copy
__global__ void conv_f2b(const float* __restrict__ in, unsigned short* __restrict__ out, int n) {
  int i = blockIdx.x * blockDim.x + threadIdx.x;
  int stride = gridDim.x * blockDim.x;
  for (; i < n; i += stride) out[i] = f2bf(in[i]);
}

// ---------------- bf16 MFMA GEMM ----------------
// C = A @ Bt^T. BM=BN=128, BK=32, 256 thr = 4 waves (2x2), wave tile 64x64,
// mfma 16x16x32 bf16, global_load_lds(16B) staging. OT = float or ushort (bf16 C).
// SWZ=1: XCD-chunked block swizzle (requires nwg % 8 == 0).
template <int LDA, int LDB, int LDC, int NREAL, int KCHUNK, int KTOT, int SWZ, typename OT>
__global__ __launch_bounds__(256)
void gemm_bf16_t(const unsigned short* __restrict__ A, long az,
                 const unsigned short* __restrict__ Bt, long bz,
                 OT* __restrict__ C, long cz) {
  __shared__ __align__(16) unsigned short As[128 * 32];  // [row][k] 8 KB
  __shared__ __align__(16) unsigned short Bs[128 * 32];  // [col][k] 8 KB
  int bx = blockIdx.x, by = blockIdx.y, bz_ = blockIdx.z;
  if (SWZ) {
    int gx = gridDim.x, gy = gridDim.y;
    int nwg = gx * gy * gridDim.z;
    int lin = bx + gx * (by + gy * bz_);
    int q = nwg >> 3;
    int lin2 = (lin & 7) * q + (lin >> 3);   // XCD-chunked, bijective (nwg%8==0)
    bx = lin2 % gx; by = (lin2 / gx) % gy; bz_ = lin2 / (gx * gy);
  }
  const int z = bz_;
  A  += (size_t)z * az;
  Bt += (size_t)z * bz;
  C  += (size_t)z * cz;
  int ks, ke;
  if (KCHUNK > 0) {
    ks = z * KCHUNK;
    ke = (ks + KCHUNK < KTOT) ? (ks + KCHUNK) : KTOT;
  } else {
    ks = 0; ke = KTOT;
  }
  const int t = threadIdx.x;
  const int w = t >> 6, lane = t & 63;
  const int m0 = by * 128, n0 = bx * 128;
  const int c0 = t, c1 = t + 256;
  const int ra0 = c0 >> 2, ca0 = (c0 & 3) * 8;
  const int ra1 = c1 >> 2, ca1 = (c1 & 3) * 8;
  const unsigned short* gA0 = A + (size_t)(m0 + ra0) * LDA + ca0;
  const unsigned short* gA1 = A + (size_t)(m0 + ra1) * LDA + ca1;
  const unsigned short* gB0 = Bt + (size_t)(n0 + ra0) * LDB + ca0;
  const unsigned short* gB1 = Bt + (size_t)(n0 + ra1) * LDB + ca1;
  unsigned short* lA0 = As + (size_t)w * 512;
  unsigned short* lA1 = As + (size_t)(4 + w) * 512;
  unsigned short* lB0 = Bs + (size_t)w * 512;
  unsigned short* lB1 = Bs + (size_t)(4 + w) * 512;
  const int wm = (w >> 1) * 64, wn = (w & 1) * 64;
  const int arow = lane & 15, acol = (lane >> 4) * 8;
  f32x4 acc[4][4] = {};
  for (int k = ks; k < ke; k += 32) {
    __builtin_amdgcn_global_load_lds((const __attribute__((address_space(1))) void*)(gA0 + k),
                                     (__attribute__((address_space(3))) void*)(lA0), 16, 0, 0);
    __builtin_amdgcn_global_load_lds((const __attribute__((address_space(1))) void*)(gA1 + k),
                                     (__attribute__((address_space(3))) void*)(lA1), 16, 0, 0);
    __builtin_amdgcn_global_load_lds((const __attribute__((address_space(1))) void*)(gB0 + k),
                                     (__attribute__((address_space(3))) void*)(lB0), 16, 0, 0);
    __builtin_amdgcn_global_load_lds((const __attribute__((address_space(1))) void*)(gB1 + k),
                                     (__attribute__((address_space(3))) void*)(lB1), 16, 0, 0);
    __syncthreads();
    short8 a[4], b[4];
#pragma unroll
    for (int i = 0; i < 4; i++)
      a[i] = *(const short8*)&As[(wm + i * 16 + arow) * 32 + acol];
#pragma unroll
    for (int j = 0; j < 4; j++)
      b[j] = *(const short8*)&Bs[(wn + j * 16 + arow) * 32 + acol];
#pragma unroll
    for (int i = 0; i < 4; i++)
#pragma unroll
      for (int j = 0; j < 4; j++)
        acc[i][j] = __builtin_amdgcn_mfma_f32_16x16x32_bf16(a[i], b[j], acc[i][j], 0, 0, 0);
    __syncthreads();
  }
  // C/D layout (m89-verified): col = lane&15, row = (lane>>4)*4 + reg
  const int crow = (lane >> 4) * 4, ccol = lane & 15;
#pragma unroll
  for (int i = 0; i < 4; i++)
#pragma unroll
    for (int j = 0; j < 4; j++) {
      int gc = n0 + wn + j * 16 + ccol;
      if (gc < NREAL) {
#pragma unroll
        for (int r = 0; r < 4; r++)
          st_out(&C[(size_t)(m0 + wm + i * 16 + crow + r) * LDC + gc], acc[i][j][r]);
      }
    }
}

// sum KSPL split-K partials -> bf16 accb only (out-layer reads bf16)
__global__ void addn_kernel(const float* __restrict__ p, unsigned short* __restrict__ ob) {
  const int n = NN * DOUT;
  int i = blockIdx.x * blockDim.x + threadIdx.x;
  int stride = gridDim.x * blockDim.x;
  for (; i < n; i += stride) {
    float v = 0.f;
#pragma unroll
    for (int z = 0; z < KSPL; z++) v += p[(size_t)z * n + i];
    ob[i] = f2bf(v);
  }
}

// ---------------- thin-M fp32 GEMM (MLP head: M=128) ----------------
template <int K, int KS>
__global__ __launch_bounds__(256)
void gemm_thin(const float* __restrict__ A, const float* __restrict__ B,
               float* __restrict__ P, int N) {
  constexpr int KC = K / KS;            // 125 for K=1000, KS=8
  __shared__ float Ash[128][KC + 3];
  int t = threadIdx.x;
  int tx = t & 63, ty = t >> 6;
  int n0 = blockIdx.x * 64, kz = blockIdx.y;
  int ks = kz * KC;
  for (int idx = t; idx < 128 * KC; idx += 256) {
    int r = idx / KC, c = idx - r * KC;
    Ash[r][c] = A[(size_t)r * K + ks + c];
  }
  __syncthreads();
  int nn = n0 + tx; if (nn > N - 1) nn = N - 1;   // clamp B loads (write guarded)
  const float* Bp = B + (size_t)ks * N + nn;
  int m0 = ty * 32;
  float acc[32] = {};
  for (int k4 = 0; k4 < KC / 4; k4++) {
    int k = k4 * 4;
    float w0 = Bp[(size_t)(k + 0) * N];
    float w1 = Bp[(size_t)(k + 1) * N];
    float w2 = Bp[(size_t)(k + 2) * N];
    float w3 = Bp[(size_t)(k + 3) * N];
#pragma unroll
    for (int mm = 0; mm < 32; mm++) {
      float4 a = *(const float4*)&Ash[m0 + mm][k];
      acc[mm] += a.x * w0 + a.y * w1 + a.z * w2 + a.w * w3;
    }
  }
#pragma unroll
  for (int k = (KC / 4) * 4; k < KC; k++) {
    float w0 = Bp[(size_t)k * N];
#pragma unroll
    for (int mm = 0; mm < 32; mm++) acc[mm] += Ash[m0 + mm][k] * w0;
  }
  if (n0 + tx < N) {
    float* Pp = P + (size_t)kz * 128 * N;
#pragma unroll
    for (int mm = 0; mm < 32; mm++)
      Pp[(size_t)(m0 + mm) * N + n0 + tx] = acc[mm];
  }
}

// reduce KS partials + bias (+relu if EPI==2)
template <int N, int KS, int EPI>
__global__ void thin_reduce(const float* __restrict__ P, const float* __restrict__ bias,
                            float* __restrict__ C) {
  int i = blockIdx.x * blockDim.x + threadIdx.x;
  const int total = 128 * N;
  if (i >= total) return;
  int n = i % N;
  float v = 0.f;
#pragma unroll
  for (int z = 0; z < KS; z++) v += P[(size_t)z * total + i];
  v += bias[n];
  if (EPI == 2) v = v > 0.f ? v : 0.f;
  C[i] = v;
}

// ---------------- tiled fp32 GEMM (fallback path only) ----------------
template <int BM_, int BN_, int EPI>
__global__ __launch_bounds__(256)
void gemm_t(const float* __restrict__ A, const float* __restrict__ B,
            float* __restrict__ C, const float* __restrict__ bias,
            int M, int N, int K, int lda, int ldb, int ldc, int accum,
            long bz, long cz) {
  constexpr int MR = BM_ / 16, NR = BN_ / 16;
  __shared__ float As[16][BM_ + 4];
  __shared__ float Bs[16][BN_ + 4];
  const float* Bp = B + (size_t)blockIdx.z * bz;
  float* Cp = C + (size_t)blockIdx.z * cz;
  int tx = threadIdx.x, ty = threadIdx.y;
  int tid = ty * 16 + tx;
  int m0 = blockIdx.y * BM_, n0 = blockIdx.x * BN_;
  float acc[MR][NR] = {};
  for (int k0 = 0; k0 < K; k0 += 16) {
#pragma unroll
    for (int p = 0; p < BM_ / 64; p++) {
      int id = tid + p * 256;
      int r = id >> 2, c4 = (id & 3) * 4;
      int gm = m0 + r;
      float v[4];
      if (gm < M && k0 + c4 + 3 < K) {
        const float4 t4 = *(const float4*)&A[(size_t)gm * lda + k0 + c4];
        v[0] = t4.x; v[1] = t4.y; v[2] = t4.z; v[3] = t4.w;
      } else {
#pragma unroll
        for (int q = 0; q < 4; q++) {
          int gk = k0 + c4 + q;
          v[q] = (gm < M && gk < K) ? A[(size_t)gm * lda + gk] : 0.0f;
        }
      }
#pragma unroll
      for (int q = 0; q < 4; q++) As[c4 + q][r] = v[q];
    }
#pragma unroll
    for (int p = 0; p < BN_ / 64; p++) {
      int id = tid + p * 256;
      int r = id / (BN_ / 4), c4 = (id % (BN_ / 4)) * 4;
      int gk = k0 + r, gn = n0 + c4;
      float v[4];
      if (gk < K && gn + 3 < N) {
        const float4 t4 = *(const float4*)&Bp[(size_t)gk * ldb + gn];
        v[0] = t4.x; v[1] = t4.y; v[2] = t4.z; v[3] = t4.w;
      } else {
#pragma unroll
        for (int q = 0; q < 4; q++)
          v[q] = (gk < K && gn + q < N) ? Bp[(size_t)gk * ldb + gn + q] : 0.0f;
      }
      *(float4*)&Bs[r][c4] = *(const float4*)v;
    }
    __syncthreads();
#pragma unroll
    for (int kk = 0; kk < 16; kk++) {
      float a[MR], b[NR];
#pragma unroll
      for (int q = 0; q < MR / 4; q++)
        *(float4*)&a[q * 4] = *(const float4*)&As[kk][ty * MR + q * 4];
#pragma unroll
      for (int q = 0; q < NR / 4; q++)
        *(float4*)&b[q * 4] = *(const float4*)&Bs[kk][tx * NR + q * 4];
#pragma unroll
      for (int i = 0; i < MR; i++)
#pragma unroll
        for (int j = 0; j < NR; j++) acc[i][j] += a[i] * b[j];
    }
    __syncthreads();
  }
#pragma unroll
  for (int i = 0; i < MR; i++) {
    int gm = m0 + ty * MR + i;
    if (gm >= M) continue;
#pragma unroll
    for (int j = 0; j < NR; j++) {
      int gn = n0 + tx * NR + j;
      if (gn >= N) continue;
      float r = acc[i][j];
      if (accum) r += Cp[(size_t)gm * ldc + gn];
      if (EPI == 2) { r += bias[gn]; r = r > 0.f ? r : 0.f; }
      else if (EPI == 3) { r += bias[gn]; }
      Cp[(size_t)gm * ldc + gn] = r;
    }
  }
}

// ---------------- pooling ----------------

__global__ void pool_prep(const int* __restrict__ batch, int* __restrict__ startg, int* __restrict__ cntg) {
  int n = blockIdx.x * blockDim.x + threadIdx.x;
  if (n >= NN) return;
  int b = batch[n];
  if (n == 0 || batch[n - 1] != b) startg[b] = n;
  atomicAdd(&cntg[b], 1);
}

__global__ void pool_kernel(const float* __restrict__ outb,
                            const int* __restrict__ startg, const int* __restrict__ cntg,
                            float* __restrict__ pooled) {
  int g = blockIdx.x, t = threadIdx.x;
  int st = startg[g], c = cntg[g];
  for (int ch = t; ch < DOUT; ch += 256) {
    float s = 0.f;
    for (int k = 0; k < c; k++) s += outb[(size_t)(st + k) * DOUT + ch];
    pooled[(size_t)g * DOUT + ch] = s / (float)(c > 0 ? c : 1);
  }
}

// ---------------- launch ----------------

static inline int cdiv(int a, int b) { return (a + b - 1) / b; }

extern "C" void kernel_launch(void* const* d_in, const int* in_sizes, int n_in,
                              void* d_out, int out_size, void* d_ws, size_t ws_size,
                              hipStream_t stream) {
  const float* x        = (const float*)d_in[0];
  const int*   ei       = (const int*)d_in[1];
  const int*   batch    = (const int*)d_in[2];
  const float* W_heads  = (const float*)d_in[3];
  const float* a1_heads = (const float*)d_in[4];
  const float* a2_heads = (const float*)d_in[5];
  const float* W_out    = (const float*)d_in[6];
  const float* a1_out   = (const float*)d_in[7];
  const float* a2_out   = (const float*)d_in[8];
  const float* W1       = (const float*)d_in[9];
  const float* b1       = (const float*)d_in[10];
  const float* W2       = (const float*)d_in[11];
  const float* b2       = (const float*)d_in[12];
  float* outd = (float*)d_out;
  (void)in_sizes; (void)n_in; (void)out_size;

  char* w = (char*)d_ws;
  size_t off = 0;
  auto alloc = [&](size_t bytes) {
    void* p = w + off;
    off += (bytes + 255) & ~(size_t)255;
    return p;
  };
  auto al = [](size_t b) { return (b + 255) & ~(size_t)255; };

  // common small buffers
  unsigned char* mask = (unsigned char*)alloc((size_t)NN * NN);      // 4 MB
  int*   nbr    = (int*)alloc((size_t)NN * CAP * 4);                 // 1.3 MB
  int*   deg    = (int*)alloc((size_t)NN * 4);
  float* acc    = (float*)alloc((size_t)NN * DOUT * 4);              // 8.2 MB (fallback + MLP partials)
  unsigned short* accb = (unsigned short*)alloc((size_t)NN * DOUT * 2); // 4.1 MB
  float* outb   = (float*)alloc((size_t)NN * DOUT * 4);              // 8.2 MB
  float* f1o    = (float*)alloc((size_t)NN * 4);
  float* f2o    = (float*)alloc((size_t)NN * 4);
  float* cso    = (float*)alloc((size_t)DOUT * 4);
  float* pooled = (float*)alloc((size_t)NG * DOUT * 4);
  float* hid    = (float*)alloc((size_t)NG * MLPD * 4);
  int*   startg = (int*)alloc((size_t)NG * 4);
  int*   cntg   = (int*)alloc((size_t)NG * 4);
  size_t off_common = off;

  // batched-path big buffers
  size_t need_batched = off_common
      + al((size_t)NN * HCAT * 2)           // Whb (bf16) / split-K partials
      + al((size_t)NN * HCAT * 2)           // hcat bf16
      + al((size_t)NPAD * HCAT * 2)         // W_out^T bf16 (padded)
      + al((size_t)NN * FP * 2)             // x bf16
      + al((size_t)NH * HP * FP * 2)        // W_heads^T bf16
      + al((size_t)NN * NH * CAP * 4)       // att_c
      + al((size_t)NH * NN * 4) * 2         // f1_all + f2_all
      + al((size_t)NH * HHID * 4);          // cs_all
  bool batched = ws_size >= need_batched;

  // 1) adjacency mask + CSR (dedupes duplicate edges like .at[].set(1.0))
  zero_words<<<4096, 256, 0, stream>>>((unsigned int*)mask, NN * NN / 4);
  scatter_mask<<<cdiv(NE, 256), 256, 0, stream>>>(ei, mask);
  build_csr<<<NN / 4, 256, 0, stream>>>(mask, nbr, deg);

  if (batched) {
    unsigned short* Whb   = (unsigned short*)alloc((size_t)NN * HCAT * 2);  // 49.2 MB
    unsigned short* hcatb = (unsigned short*)alloc((size_t)NN * HCAT * 2);  // 49.2 MB
    unsigned short* Wt    = (unsigned short*)alloc((size_t)NPAD * HCAT * 2);// 24.6 MB
    unsigned short* xb    = (unsigned short*)alloc((size_t)NN * FP * 2);    // 1.3 MB
    unsigned short* Wth   = (unsigned short*)alloc((size_t)NH * HP * FP * 2);// 8.2 MB
    float* att_c  = (float*)alloc((size_t)NN * NH * CAP * 4);               // 26.2 MB
    float* f1a    = (float*)alloc((size_t)NH * NN * 4);
    float* f2a    = (float*)alloc((size_t)NH * NN * 4);
    float* csa    = (float*)alloc((size_t)NH * HHID * 4);
    // split-K partials reuse Whb's space (dead after spmm_pv):
    // KSPL=6 * NN*DOUT*4 = 49.15 MB <= 49.2 MB
    float* partC = (float*)Whb;

    // 2) Whb[:, hd*600:+600] = bf16(x @ W_heads[hd]) via MFMA, one launch z=heads
    conv_x_bf16<<<NN, FP, 0, stream>>>(x, xb);
    convT_gen<<<dim3(FP / 32, HP / 32, NH), dim3(32, 8), 0, stream>>>(
        W_heads, Wth, FF, HHID, HHID, (long)FF * HHID, FP, (long)HP * FP);
    gemm_bf16_t<FP, FP, HCAT, HHID, 0, FP, 0, unsigned short>
        <<<dim3(HP / 128, NN / 128, NH), 256, 0, stream>>>(
        xb, 0L, Wth, (long)HP * FP, Whb, (long)HHID);
    // 3) per-(node, head) attention logits halves + zero-deg fallback colsums
    f12_bf16<<<dim3(NN, NH), 64, 0, stream>>>(Whb, HCAT, HHID,
                                              a1_heads, a2_heads, HHID, f1a, f2a);
    zero_words<<<12, 256, 0, stream>>>((unsigned int*)csa, NH * HHID);
    colsum_at_bf16<<<dim3(cdiv(HCAT, 256), NN / 64), 256, 0, stream>>>(Whb, HCAT, HCAT, csa);
    // 3b) W_out -> bf16 transposed (B^T layout for contiguous MFMA B-frags)
    convT_gen<<<dim3(HCAT / 32, NPAD / 32, 1), dim3(32, 8), 0, stream>>>(
        W_out, Wt, HCAT, DOUT, DOUT, 0L, HCAT, 0L);
    // 4) softmax precompute + column-chunked PV gather (L2-locality via chunk->XCD pin)
    att_pre<<<dim3(NN, NH / 4), 256, 0, stream>>>(f1a, f2a, nbr, deg, att_c);
    spmm_pv<<<dim3(PVC, NN / PVR), 256, 0, stream>>>(Whb, att_c, nbr, deg, csa, hcatb);
    // 5) acc = hcat @ W_out via bf16 MFMA, split-K=6 (768 blocks, XCD swizzle)
    gemm_bf16_t<HCAT, HCAT, DOUT, DOUT, KCH, HCAT, 1, float>
        <<<dim3(NPAD / 128, NN / 128, KSPL), 256, 0, stream>>>(
        hcatb, 0L, Wt, 0L, partC, (long)NN * DOUT);
    addn_kernel<<<2048, 256, 0, stream>>>(partC, accb);
    // 6) output attention layer (all-bf16 inputs)
    f12_bf16<<<dim3(NN, 1), 64, 0, stream>>>(accb, DOUT, DOUT, a1_out, a2_out, 0, f1o, f2o);
    zero_words<<<1, 256, 0, stream>>>((unsigned int*)cso, DOUT);
    colsum_at_bf16<<<dim3(cdiv(DOUT, 256), NN / 64), 256, 0, stream>>>(accb, DOUT, DOUT, cso);
    spmm_att_o<<<dim3(NN), 128, 0, stream>>>(accb, f1o, f2o, nbr, deg, cso, outb);
  } else {
    // fallback: per-head pipeline (fp32 GEMM + fp32 spmm)
    float* Wh   = (float*)alloc((size_t)NN * HHID * 4);
    float* hout = (float*)alloc((size_t)NN * HHID * 4);
    float* f1   = (float*)alloc((size_t)NN * 4);
    float* f2   = (float*)alloc((size_t)NN * 4);
    float* cs   = (float*)alloc((size_t)HHID * 4);
    zero_words<<<8000, 256, 0, stream>>>((unsigned int*)acc, NN * DOUT);
    for (int hd = 0; hd < NH; hd++) {
      gemm_t<64, 64, 0><<<dim3(cdiv(HHID, 64), cdiv(NN, 64), 1), dim3(16, 16), 0, stream>>>(
          x, W_heads + (size_t)hd * FF * HHID, Wh, nullptr,
          NN, HHID, FF, FF, HHID, HHID, 0, 0L, 0L);
      f12_kernel<<<dim3(NN, 1), 64, 0, stream>>>(Wh, HHID, HHID,
          a1_heads + (size_t)hd * HHID, a2_heads + (size_t)hd * HHID, 0, f1, f2);
      colsum_kernel<<<dim3(cdiv(HHID, 256), 1), 256, 0, stream>>>(Wh, HHID, HHID, cs);
      spmm_att<float><<<dim3(NN, 1), 256, 0, stream>>>(Wh, HHID, HHID, f1, f2,
                                                       nbr, deg, cs, hout, HHID);
      gemm_t<64, 64, 0><<<dim3(cdiv(DOUT, 64), cdiv(NN, 64), 1), dim3(16, 16), 0, stream>>>(
          hout, W_out + (size_t)hd * HHID * DOUT, acc, nullptr,
          NN, DOUT, HHID, HHID, DOUT, DOUT, 1, 0L, 0L);
    }
    conv_f2b<<<2048, 256, 0, stream>>>(acc, accb, NN * DOUT);
    // 6) output attention layer (fp32 logits from acc)
    f12_kernel<<<dim3(NN, 1), 64, 0, stream>>>(acc, DOUT, DOUT, a1_out, a2_out, 0, f1o, f2o);
    zero_words<<<1, 256, 0, stream>>>((unsigned int*)cso, DOUT);
    colsum_at_f32<<<dim3(cdiv(DOUT, 256), NN / 64), 256, 0, stream>>>(acc, DOUT, DOUT, cso);
    spmm_att_o<<<dim3(NN), 128, 0, stream>>>(accb, f1o, f2o, nbr, deg, cso, outb);
  }

  // 7) global mean pool (batch is sorted)
  zero_words<<<1, 256, 0, stream>>>((unsigned int*)startg, NG * 2);  // startg+cntg contiguous
  pool_prep<<<NN / 256, 256, 0, stream>>>(batch, startg, cntg);
  pool_kernel<<<NG, 256, 0, stream>>>(outb, startg, cntg, pooled);

  // 8) MLP head — thin-M split-K GEMMs (acc is dead here in both paths; reuse for partials)
  float* mlpP = acc;   // 8*128*1000*4 = 4.1 MB <= 8.2 MB
  gemm_thin<DOUT, 8><<<dim3(cdiv(MLPD, 64), 8), 256, 0, stream>>>(pooled, W1, mlpP, MLPD);
  thin_reduce<MLPD, 8, 2><<<cdiv(NG * MLPD, 256), 256, 0, stream>>>(mlpP, b1, hid);
  gemm_thin<MLPD, 8><<<dim3(cdiv(NOUTD, 64), 8), 256, 0, stream>>>(hid, W2, mlpP, NOUTD);
  thin_reduce<NOUTD, 8, 3><<<cdiv(NG * NOUTD, 256), 256, 0, stream>>>(mlpP, b2, outd);
}

// Round 12
// 377.162 us; speedup vs baseline: 1.0852x; 1.0014x over previous
//
#include <hip/hip_runtime.h>
#include <math.h>

// Problem constants (from setup_inputs)
#define NN   2048   // nodes
#define FF   300    // input features
#define FP   320    // FF padded to 32 multiple for MFMA K
#define NH   20     // heads
#define HHID 600    // per-head hidden
#define HP   640    // HHID padded to 128 multiple for MFMA N
#define HCAT (NH * HHID)  // 12000
#define DOUT 1000   // out_att width
#define NPAD 1024   // DOUT padded to 128 multiple for MFMA GEMM
#define MLPD 1000   // MLP hidden
#define NOUTD 768   // final output
#define NE   32768  // edges
#define NG   128    // graphs
#define CAP  160    // max neighbors kept per row (Poisson(16) tail safe)
#define KSPL 6      // split-K for K=12000 GEMM (768 blocks = 3/CU; 8 regressed, r8)
#define KCH  2016   // K chunk (x32); last chunk = 12000-5*2016 = 1920
#define PVC  16     // PV column chunks (gridDim.x -> XCD pin = chunk%8)
#define PVR  8      // PV rows per block (r6 champion value)
#define PVU  94     // short8-units per PV chunk (1500 total; last chunk = 90)

typedef __attribute__((ext_vector_type(8))) short short8;   // 8 bf16 (A/B frag)
typedef __attribute__((ext_vector_type(4))) float f32x4;    // C/D frag

__device__ __forceinline__ unsigned short f2bf(float f) {
  // round-to-nearest-even fp32 -> bf16
  unsigned int u = __float_as_uint(f);
  u += 0x7fffu + ((u >> 16) & 1u);
  return (unsigned short)(u >> 16);
}
__device__ __forceinline__ float bf2f(unsigned short u) {
  return __uint_as_float(((unsigned int)u) << 16);
}
__device__ __forceinline__ void st_out(float* p, float v) { *p = v; }
__device__ __forceinline__ void st_out(unsigned short* p, float v) { *p = f2bf(v); }

// ---------------- utility kernels ----------------

__global__ void zero_words(unsigned int* __restrict__ p, int n) {
  int i = blockIdx.x * blockDim.x + threadIdx.x;
  int stride = gridDim.x * blockDim.x;
  for (; i < n; i += stride) p[i] = 0u;
}

__global__ void scatter_mask(const int* __restrict__ ei, unsigned char* __restrict__ mask) {
  int e = blockIdx.x * blockDim.x + threadIdx.x;
  if (e < NE) {
    int s = ei[e], d = ei[NE + e];
    mask[(size_t)s * NN + d] = 1;
  }
}

// one wave per row: dword-load the adjacency row, ballot-compact per byte lane
__global__ void build_csr(const unsigned char* __restrict__ mask,
                          int* __restrict__ nbr, int* __restrict__ deg) {
  int wave = threadIdx.x >> 6, lane = threadIdx.x & 63;
  int i = blockIdx.x * 4 + wave;
  if (i >= NN) return;
  const unsigned* roww = (const unsigned*)(mask + (size_t)i * NN);
  int cnt = 0;
  for (int c0 = 0; c0 < NN; c0 += 256) {        // 256 bytes per iter
    unsigned word = roww[(c0 >> 2) + lane];
#pragma unroll
    for (int b = 0; b < 4; b++) {
      bool p = ((word >> (8 * b)) & 0xffu) != 0u;
      unsigned long long bal = __ballot(p);
      if (p) {
        int pos = cnt + (int)__popcll(bal & ((1ull << lane) - 1ull));
        if (pos < CAP) nbr[(size_t)i * CAP + pos] = c0 + lane * 4 + b;
      }
      cnt += (int)__popcll(bal);
    }
  }
  if (lane == 0) deg[i] = cnt < CAP ? cnt : CAP;
}

// ---------------- f1/f2 + colsum (fallback + out-layer) ----------------

__global__ void f12_kernel(const float* __restrict__ Wh, int ldw, int h,
                           const float* __restrict__ a1, const float* __restrict__ a2,
                           int astride,
                           float* __restrict__ f1, float* __restrict__ f2) {
  int i = blockIdx.x, hd = blockIdx.y;
  int lane = threadIdx.x;
  const float* r = Wh + (size_t)i * ldw + (size_t)hd * h;
  const float* A1 = a1 + (size_t)hd * astride;
  const float* A2 = a2 + (size_t)hd * astride;
  float s1 = 0.f, s2 = 0.f;
  for (int c = lane; c < h; c += 64) {
    float w = r[c];
    s1 += w * A1[c];
    s2 += w * A2[c];
  }
  for (int off = 32; off; off >>= 1) {
    s1 += __shfl_down(s1, off);
    s2 += __shfl_down(s2, off);
  }
  if (lane == 0) { f1[(size_t)hd * NN + i] = s1; f2[(size_t)hd * NN + i] = s2; }
}

// bf16 input, short8-vectorized; h must be divisible by 8 (out-layer on accb)
__global__ void f12_bf16(const unsigned short* __restrict__ Wh, int ldw, int h,
                         const float* __restrict__ a1, const float* __restrict__ a2,
                         int astride,
                         float* __restrict__ f1, float* __restrict__ f2) {
  int i = blockIdx.x, hd = blockIdx.y;
  int lane = threadIdx.x;
  const unsigned short* r = Wh + (size_t)i * ldw + (size_t)hd * h;
  const float* A1 = a1 + (size_t)hd * astride;
  const float* A2 = a2 + (size_t)hd * astride;
  float s1 = 0.f, s2 = 0.f;
  for (int c8 = lane; c8 < h / 8; c8 += 64) {
    short8 v = *(const short8*)(r + (size_t)c8 * 8);
#pragma unroll
    for (int j = 0; j < 8; j++) {
      float w = bf2f((unsigned short)v[j]);
      s1 += w * A1[c8 * 8 + j];
      s2 += w * A2[c8 * 8 + j];
    }
  }
  for (int off = 32; off; off >>= 1) {
    s1 += __shfl_down(s1, off);
    s2 += __shfl_down(s2, off);
  }
  if (lane == 0) { f1[(size_t)hd * NN + i] = s1; f2[(size_t)hd * NN + i] = s2; }
}

// serial colsum (fallback path only)
__global__ void colsum_kernel(const float* __restrict__ Wh, int ldw, int h,
                              float* __restrict__ cs) {
  int hd = blockIdx.y;
  int c = blockIdx.x * blockDim.x + threadIdx.x;
  if (c >= h) return;
  size_t off = (size_t)hd * h + c;
  float s = 0.f;
  for (int i = 0; i < NN; i++) s += Wh[(size_t)i * ldw + off];
  cs[(size_t)hd * h + c] = s;
}

// row-parallel colsum + atomics: grid (cdiv(width,256), rows/64); cs pre-zeroed.
__global__ void colsum_at_bf16(const unsigned short* __restrict__ Wh, int ld, int width,
                               float* __restrict__ cs) {
  int c = blockIdx.x * blockDim.x + threadIdx.x;
  if (c >= width) return;
  int r0 = blockIdx.y * 64;
  float s = 0.f;
  for (int i = r0; i < r0 + 64; i++) s += bf2f(Wh[(size_t)i * ld + c]);
  atomicAdd(&cs[c], s);
}

__global__ void colsum_at_f32(const float* __restrict__ Wh, int ld, int width,
                              float* __restrict__ cs) {
  int c = blockIdx.x * blockDim.x + threadIdx.x;
  if (c >= width) return;
  int r0 = blockIdx.y * 64;
  float s = 0.f;
  for (int i = r0; i < r0 + 64; i++) s += Wh[(size_t)i * ld + c];
  atomicAdd(&cs[c], s);
}

// ---------------- sparse attention (softmax + PV + elu) ----------------

// fp32 fallback version: one block (256 thr) per (row, head)
template <typename OT>
__global__ __launch_bounds__(256)
void spmm_att(const float* __restrict__ Wh, int ldw, int h,
              const float* __restrict__ f1, const float* __restrict__ f2,
              const int* __restrict__ nbr, const int* __restrict__ deg,
              const float* __restrict__ cs,
              OT* __restrict__ outp, int ldo) {
  __shared__ float att[CAP];
  __shared__ int   nb[CAP];
  __shared__ float red[256];
  int i = blockIdx.x, hd = blockIdx.y;
  int t = threadIdx.x;
  int d = deg[i];
  size_t hoff = (size_t)hd * h;
  if (d > 0) {
    float fi = f1[(size_t)hd * NN + i];
    const float* F2 = f2 + (size_t)hd * NN;
    float lmax = -INFINITY;
    for (int k = t; k < d; k += 256) {
      int j = nbr[(size_t)i * CAP + k];
      nb[k] = j;
      float e = fi + F2[j];
      e = e > 0.f ? e : 0.02f * e;   // leaky_relu slope 0.02
      att[k] = e;
      lmax = fmaxf(lmax, e);
    }
    red[t] = lmax; __syncthreads();
    for (int s = 128; s; s >>= 1) { if (t < s) red[t] = fmaxf(red[t], red[t + s]); __syncthreads(); }
    float m = red[0]; __syncthreads();
    float ls = 0.f;
    for (int k = t; k < d; k += 256) { float p = expf(att[k] - m); att[k] = p; ls += p; }
    red[t] = ls; __syncthreads();
    for (int s = 128; s; s >>= 1) { if (t < s) red[t] += red[t + s]; __syncthreads(); }
    float inv = 1.0f / red[0]; __syncthreads();
    for (int k = t; k < d; k += 256) att[k] *= inv;
    __syncthreads();
    for (int c = t; c < h; c += 256) {
      float s = 0.f;
      for (int k = 0; k < d; k++) s += att[k] * Wh[(size_t)nb[k] * ldw + hoff + c];
      s = s > 0.f ? s : (expf(s) - 1.0f);  // elu
      st_out(&outp[(size_t)i * ldo + hoff + c], s);
    }
  } else {
    const float inv = 1.0f / (float)NN;
    for (int c = t; c < h; c += 256) {
      float s = cs[hoff + c] * inv;
      s = s > 0.f ? s : (expf(s) - 1.0f);
      st_out(&outp[(size_t)i * ldo + hoff + c], s);
    }
  }
}

// precompute normalized attention weights: att_c[i][hd][k] (k < deg[i]).
// grid (NN, NH/4), block 256 = 4 waves; wave w -> head by*4+w.
__global__ __launch_bounds__(256)
void att_pre(const float* __restrict__ f1, const float* __restrict__ f2,
             const int* __restrict__ nbr, const int* __restrict__ deg,
             float* __restrict__ att_c) {
  __shared__ int   nb_sh[CAP];
  __shared__ float att_sh[4][CAP];
  int i = blockIdx.x;
  int t = threadIdx.x, w = t >> 6, lane = t & 63;
  int hd = blockIdx.y * 4 + w;
  int d = deg[i];
  if (d == 0) return;   // uniform across block: safe before syncthreads
  for (int k = t; k < d; k += 256) nb_sh[k] = nbr[(size_t)i * CAP + k];
  __syncthreads();
  float fi = f1[(size_t)hd * NN + i];
  const float* F2 = f2 + (size_t)hd * NN;
  float lmax = -INFINITY;
  for (int k = lane; k < d; k += 64) {
    float e = fi + F2[nb_sh[k]];
    e = e > 0.f ? e : 0.02f * e;   // leaky_relu slope 0.02
    att_sh[w][k] = e;
    lmax = fmaxf(lmax, e);
  }
  for (int off = 32; off; off >>= 1) lmax = fmaxf(lmax, __shfl_xor(lmax, off));
  float ls = 0.f;
  for (int k = lane; k < d; k += 64) {
    float p = expf(att_sh[w][k] - lmax);
    att_sh[w][k] = p; ls += p;
  }
  for (int off = 32; off; off >>= 1) ls += __shfl_xor(ls, off);
  float inv = 1.0f / ls;
  float* ao = att_c + ((size_t)i * NH + hd) * CAP;
  for (int k = lane; k < d; k += 64) ao[k] = att_sh[w][k] * inv;
}

// column-chunked PV gather + elu. grid (PVC, NN/PVR) — chunk is the FAST grid dim
// so all blocks of chunk c land on XCD c%8 (gridDim.x=16 multiple of 8).
__global__ __launch_bounds__(256)
void spmm_pv(const unsigned short* __restrict__ Whb,   // [NN][HCAT] bf16
             const float* __restrict__ att_c,          // [NN][NH][CAP]
             const int* __restrict__ nbr, const int* __restrict__ deg,
             const float* __restrict__ cs,
             unsigned short* __restrict__ outp) {      // [NN][HCAT] bf16
  __shared__ int nb_sh[PVR][CAP];
  __shared__ int d_sh[PVR];
  int t = threadIdx.x;
  int r0 = blockIdx.y * PVR;
  int u0 = blockIdx.x * PVU;
  int nu = (u0 + PVU <= HCAT / 8) ? PVU : (HCAT / 8 - u0);
  if (t < PVR) d_sh[t] = deg[r0 + t];
  for (int q = t; q < PVR * CAP; q += 256) {
    int r = q / CAP, k = q - r * CAP;
    nb_sh[r][k] = nbr[(size_t)(r0 + r) * CAP + k];
  }
  __syncthreads();
  const float invn = 1.0f / (float)NN;
  int total = PVR * nu;
  for (int q = t; q < total; q += 256) {
    int r = q / nu, u = q - r * nu;
    int i = r0 + r;
    int gu = u0 + u;                       // global short8 unit
    int hd = gu / (HHID / 8);              // 75 units per head
    int d = d_sh[r];
    const unsigned short* base = Whb + (size_t)gu * 8;
    unsigned short o8[8];
    if (d > 0) {
      const float* av = att_c + ((size_t)i * NH + hd) * CAP;
      float a8[8] = {};
      for (int k = 0; k < d; k++) {
        float a = av[k];
        short8 v = *(const short8*)(base + (size_t)nb_sh[r][k] * HCAT);
#pragma unroll
        for (int j = 0; j < 8; j++) a8[j] += a * bf2f((unsigned short)v[j]);
      }
#pragma unroll
      for (int j = 0; j < 8; j++) {
        float s = a8[j];
        s = s > 0.f ? s : (expf(s) - 1.0f);   // elu
        o8[j] = f2bf(s);
      }
    } else {
#pragma unroll
      for (int j = 0; j < 8; j++) {
        float s = cs[(size_t)gu * 8 + j] * invn;
        s = s > 0.f ? s : (expf(s) - 1.0f);
        o8[j] = f2bf(s);
      }
    }
    *(short8*)(outp + (size_t)i * HCAT + (size_t)gu * 8) = *(const short8*)o8;
  }
}

// out layer, bf16 in / fp32 out: grid (NN), block 128; 125 short8 chunks of DOUT=1000
__global__ __launch_bounds__(128)
void spmm_att_o(const unsigned short* __restrict__ Wh,   // [NN][DOUT] bf16
                const float* __restrict__ f1, const float* __restrict__ f2,
                const int* __restrict__ nbr, const int* __restrict__ deg,
                const float* __restrict__ cs,
                float* __restrict__ outp) {              // [NN][DOUT] fp32
  __shared__ int   nb_sh[CAP];
  __shared__ float att_sh[CAP];
  __shared__ float red[128];
  int i = blockIdx.x, t = threadIdx.x;
  int d = deg[i];
  if (d > 0) {
    float fi = f1[i];
    float lmax = -INFINITY;
    for (int k = t; k < d; k += 128) {
      int j = nbr[(size_t)i * CAP + k];
      nb_sh[k] = j;
      float e = fi + f2[j];
      e = e > 0.f ? e : 0.02f * e;
      att_sh[k] = e;
      lmax = fmaxf(lmax, e);
    }
    red[t] = lmax; __syncthreads();
    for (int s = 64; s; s >>= 1) { if (t < s) red[t] = fmaxf(red[t], red[t + s]); __syncthreads(); }
    float m = red[0]; __syncthreads();
    float ls = 0.f;
    for (int k = t; k < d; k += 128) { float p = expf(att_sh[k] - m); att_sh[k] = p; ls += p; }
    red[t] = ls; __syncthreads();
    for (int s = 64; s; s >>= 1) { if (t < s) red[t] += red[t + s]; __syncthreads(); }
    float inv = 1.0f / red[0]; __syncthreads();
    for (int k = t; k < d; k += 128) att_sh[k] *= inv;
    __syncthreads();
    for (int cc = t; cc < DOUT / 8; cc += 128) {
      float a8[8] = {};
      const unsigned short* base = Wh + (size_t)cc * 8;
      for (int k = 0; k < d; k++) {
        float av = att_sh[k];
        short8 v = *(const short8*)(base + (size_t)nb_sh[k] * DOUT);
#pragma unroll
      for (int j = 0; j < 8; j++)
          a8[j] += av * bf2f((unsigned short)v[j]);
      }
      float o[8];
#pragma unroll
      for (int j = 0; j < 8; j++) {
        float s = a8[j];
        o[j] = s > 0.f ? s : (expf(s) - 1.0f);
      }
      *(float4*)(outp + (size_t)i * DOUT + (size_t)cc * 8)     = make_float4(o[0], o[1], o[2], o[3]);
      *(float4*)(outp + (size_t)i * DOUT + (size_t)cc * 8 + 4) = make_float4(o[4], o[5], o[6], o[7]);
    }
  } else {
    const float invn = 1.0f / (float)NN;
    for (int c = t; c < DOUT; c += 128) {
      float s = cs[c] * invn;
      outp[(size_t)i * DOUT + c] = s > 0.f ? s : (expf(s) - 1.0f);
    }
  }
}

// ---------------- bf16 conversion kernels ----------------

// x [NN][FF] fp32 -> xb [NN][FP] bf16 (zero-padded K)
__global__ void conv_x_bf16(const float* __restrict__ x, unsigned short* __restrict__ xb) {
  int i = blockIdx.x, t = threadIdx.x;   // FP=320 threads
  float v = (t < FF) ? x[(size_t)i * FF + t] : 0.0f;
  xb[(size_t)i * FP + t] = f2bf(v);
}

// W [K][N] fp32 (z-batched, stride wz) -> Wt [Npad][ldt] bf16, Wt[n][k] = W[k][n], 0-pad.
__global__ void convT_gen(const float* __restrict__ W, unsigned short* __restrict__ Wt,
                          int K, int N, int ldw, long wz, int ldt, long tz) {
  __shared__ float tile[32][33];
  const float* Wp = W + (size_t)blockIdx.z * wz;
  unsigned short* Tp = Wt + (size_t)blockIdx.z * tz;
  int k0 = blockIdx.x * 32, n0 = blockIdx.y * 32;
  int tx = threadIdx.x, ty = threadIdx.y;
#pragma unroll
  for (int r = ty; r < 32; r += 8) {
    int kk = k0 + r, n = n0 + tx;
    tile[r][tx] = (kk < K && n < N) ? Wp[(size_t)kk * ldw + n] : 0.0f;
  }
  __syncthreads();
#pragma unroll
  for (int r = ty; r < 32; r += 8) {
    Tp[(size_t)(n0 + r) * ldt + k0 + tx] = f2bf(tile[tx][r]);
  }
}

// fp32 -> bf16 flat copy
__global__ void conv_f2b(const float* __restrict__ in, unsigned short* __restrict__ out, int n) {
  int i = blockIdx.x * blockDim.x + threadIdx.x;
  int stride = gridDim.x * blockDim.x;
  for (; i < n; i += stride) out[i] = f2bf(in[i]);
}

// ---------------- bf16 MFMA GEMM ----------------
// C = A @ Bt^T. BM=BN=128, BK=32, 256 thr = 4 waves (2x2), wave tile 64x64,
// mfma 16x16x32 bf16, global_load_lds(16B) staging. OT = float or ushort (bf16 C).
// SWZ=1: XCD-chunked block swizzle (requires nwg % 8 == 0).
// FUSE=1: fused epilogue computes f1/f2 (row dot with a1/a2 of head z, atomicAdd)
// and csa (column sums of head z, atomicAdd) from the fp32 accumulators —
// replaces separate 49 MB f12 + colsum passes. f1/f2/csa must be pre-zeroed.
template <int LDA, int LDB, int LDC, int NREAL, int KCHUNK, int KTOT, int SWZ, int FUSE,
          typename OT>
__global__ __launch_bounds__(256)
void gemm_bf16_t(const unsigned short* __restrict__ A, long az,
                 const unsigned short* __restrict__ Bt, long bz,
                 OT* __restrict__ C, long cz,
                 const float* __restrict__ a1, const float* __restrict__ a2,
                 float* __restrict__ f1, float* __restrict__ f2,
                 float* __restrict__ csa) {
  __shared__ __align__(16) unsigned short As[128 * 32];  // [row][k] 8 KB
  __shared__ __align__(16) unsigned short Bs[128 * 32];  // [col][k] 8 KB
  int bx = blockIdx.x, by = blockIdx.y, bz_ = blockIdx.z;
  if (SWZ) {
    int gx = gridDim.x, gy = gridDim.y;
    int nwg = gx * gy * gridDim.z;
    int lin = bx + gx * (by + gy * bz_);
    int q = nwg >> 3;
    int lin2 = (lin & 7) * q + (lin >> 3);   // XCD-chunked, bijective (nwg%8==0)
    bx = lin2 % gx; by = (lin2 / gx) % gy; bz_ = lin2 / (gx * gy);
  }
  const int z = bz_;
  A  += (size_t)z * az;
  Bt += (size_t)z * bz;
  C  += (size_t)z * cz;
  int ks, ke;
  if (KCHUNK > 0) {
    ks = z * KCHUNK;
    ke = (ks + KCHUNK < KTOT) ? (ks + KCHUNK) : KTOT;
  } else {
    ks = 0; ke = KTOT;
  }
  const int t = threadIdx.x;
  const int w = t >> 6, lane = t & 63;
  const int m0 = by * 128, n0 = bx * 128;
  const int c0 = t, c1 = t + 256;
  const int ra0 = c0 >> 2, ca0 = (c0 & 3) * 8;
  const int ra1 = c1 >> 2, ca1 = (c1 & 3) * 8;
  const unsigned short* gA0 = A + (size_t)(m0 + ra0) * LDA + ca0;
  const unsigned short* gA1 = A + (size_t)(m0 + ra1) * LDA + ca1;
  const unsigned short* gB0 = Bt + (size_t)(n0 + ra0) * LDB + ca0;
  const unsigned short* gB1 = Bt + (size_t)(n0 + ra1) * LDB + ca1;
  unsigned short* lA0 = As + (size_t)w * 512;
  unsigned short* lA1 = As + (size_t)(4 + w) * 512;
  unsigned short* lB0 = Bs + (size_t)w * 512;
  unsigned short* lB1 = Bs + (size_t)(4 + w) * 512;
  const int wm = (w >> 1) * 64, wn = (w & 1) * 64;
  const int arow = lane & 15, acol = (lane >> 4) * 8;
  f32x4 acc[4][4] = {};
  for (int k = ks; k < ke; k += 32) {
    __builtin_amdgcn_global_load_lds((const __attribute__((address_space(1))) void*)(gA0 + k),
                                     (__attribute__((address_space(3))) void*)(lA0), 16, 0, 0);
    __builtin_amdgcn_global_load_lds((const __attribute__((address_space(1))) void*)(gA1 + k),
                                     (__attribute__((address_space(3))) void*)(lA1), 16, 0, 0);
    __builtin_amdgcn_global_load_lds((const __attribute__((address_space(1))) void*)(gB0 + k),
                                     (__attribute__((address_space(3))) void*)(lB0), 16, 0, 0);
    __builtin_amdgcn_global_load_lds((const __attribute__((address_space(1))) void*)(gB1 + k),
                                     (__attribute__((address_space(3))) void*)(lB1), 16, 0, 0);
    __syncthreads();
    short8 a[4], b[4];
#pragma unroll
    for (int i = 0; i < 4; i++)
      a[i] = *(const short8*)&As[(wm + i * 16 + arow) * 32 + acol];
#pragma unroll
    for (int j = 0; j < 4; j++)
      b[j] = *(const short8*)&Bs[(wn + j * 16 + arow) * 32 + acol];
#pragma unroll
    for (int i = 0; i < 4; i++)
#pragma unroll
      for (int j = 0; j < 4; j++)
        acc[i][j] = __builtin_amdgcn_mfma_f32_16x16x32_bf16(a[i], b[j], acc[i][j], 0, 0, 0);
    __syncthreads();
  }
  // C/D layout (m89-verified): col = lane&15, row = (lane>>4)*4 + reg
  const int crow = (lane >> 4) * 4, ccol = lane & 15;
#pragma unroll
  for (int i = 0; i < 4; i++)
#pragma unroll
    for (int j = 0; j < 4; j++) {
      int gc = n0 + wn + j * 16 + ccol;
      if (gc < NREAL) {
#pragma unroll
        for (int r = 0; r < 4; r++)
          st_out(&C[(size_t)(m0 + wm + i * 16 + crow + r) * LDC + gc], acc[i][j][r]);
      }
    }
  if (FUSE) {
    // per-thread cols (j=0..3): gc = n0+wn+j*16+ccol; rows (i,r): m0+wm+i*16+crow+r.
    int gcj[4]; float A1v[4], A2v[4];
#pragma unroll
    for (int j = 0; j < 4; j++) {
      gcj[j] = n0 + wn + j * 16 + ccol;
      bool in = gcj[j] < NREAL;
      A1v[j] = in ? a1[(size_t)z * NREAL + gcj[j]] : 0.0f;
      A2v[j] = in ? a2[(size_t)z * NREAL + gcj[j]] : 0.0f;
    }
    // f1/f2: lanes 0-15 of each hi-group share rows, hold distinct cols -> xor 1/2/4/8.
#pragma unroll
    for (int i = 0; i < 4; i++) {
#pragma unroll
      for (int r = 0; r < 4; r++) {
        float p1 = 0.f, p2 = 0.f;
#pragma unroll
        for (int j = 0; j < 4; j++) {
          float v = acc[i][j][r];
          p1 += v * A1v[j];
          p2 += v * A2v[j];
        }
#pragma unroll
        for (int off = 1; off < 16; off <<= 1) {
          p1 += __shfl_xor(p1, off);
          p2 += __shfl_xor(p2, off);
        }
        if ((lane & 15) == 0) {
          int row = m0 + wm + i * 16 + crow + r;
          atomicAdd(&f1[(size_t)z * NN + row], p1);
          atomicAdd(&f2[(size_t)z * NN + row], p2);
        }
      }
    }
    // csa: the 4 hi-groups share cols, hold distinct rows -> xor 16/32.
#pragma unroll
    for (int j = 0; j < 4; j++) {
      float cp = 0.f;
#pragma unroll
      for (int i = 0; i < 4; i++)
#pragma unroll
        for (int r = 0; r < 4; r++) cp += acc[i][j][r];
      cp += __shfl_xor(cp, 16);
      cp += __shfl_xor(cp, 32);
      if (lane < 16 && gcj[j] < NREAL)
        atomicAdd(&csa[(size_t)z * NREAL + gcj[j]], cp);
    }
  }
}

// sum KSPL split-K partials -> bf16 accb only (out-layer reads bf16)
__global__ void addn_kernel(const float* __restrict__ p, unsigned short* __restrict__ ob) {
  const int n = NN * DOUT;
  int i = blockIdx.x * blockDim.x + threadIdx.x;
  int stride = gridDim.x * blockDim.x;
  for (; i < n; i += stride) {
    float v = 0.f;
#pragma unroll
    for (int z = 0; z < KSPL; z++) v += p[(size_t)z * n + i];
    ob[i] = f2bf(v);
  }
}

// ---------------- thin-M fp32 GEMM (MLP head: M=128) ----------------
template <int K, int KS>
__global__ __launch_bounds__(256)
void gemm_thin(const float* __restrict__ A, const float* __restrict__ B,
               float* __restrict__ P, int N) {
  constexpr int KC = K / KS;            // 125 for K=1000, KS=8
  __shared__ float Ash[128][KC + 3];
  int t = threadIdx.x;
  int tx = t & 63, ty = t >> 6;
  int n0 = blockIdx.x * 64, kz = blockIdx.y;
  int ks = kz * KC;
  for (int idx = t; idx < 128 * KC; idx += 256) {
    int r = idx / KC, c = idx - r * KC;
    Ash[r][c] = A[(size_t)r * K + ks + c];
  }
  __syncthreads();
  int nn = n0 + tx; if (nn > N - 1) nn = N - 1;   // clamp B loads (write guarded)
  const float* Bp = B + (size_t)ks * N + nn;
  int m0 = ty * 32;
  float acc[32] = {};
  for (int k4 = 0; k4 < KC / 4; k4++) {
    int k = k4 * 4;
    float w0 = Bp[(size_t)(k + 0) * N];
    float w1 = Bp[(size_t)(k + 1) * N];
    float w2 = Bp[(size_t)(k + 2) * N];
    float w3 = Bp[(size_t)(k + 3) * N];
#pragma unroll
    for (int mm = 0; mm < 32; mm++) {
      float4 a = *(const float4*)&Ash[m0 + mm][k];
      acc[mm] += a.x * w0 + a.y * w1 + a.z * w2 + a.w * w3;
    }
  }
#pragma unroll
  for (int k = (KC / 4) * 4; k < KC; k++) {
    float w0 = Bp[(size_t)k * N];
#pragma unroll
    for (int mm = 0; mm < 32; mm++) acc[mm] += Ash[m0 + mm][k] * w0;
  }
  if (n0 + tx < N) {
    float* Pp = P + (size_t)kz * 128 * N;
#pragma unroll
    for (int mm = 0; mm < 32; mm++)
      Pp[(size_t)(m0 + mm) * N + n0 + tx] = acc[mm];
  }
}

// reduce KS partials + bias (+relu if EPI==2)
template <int N, int KS, int EPI>
__global__ void thin_reduce(const float* __restrict__ P, const float* __restrict__ bias,
                            float* __restrict__ C) {
  int i = blockIdx.x * blockDim.x + threadIdx.x;
  const int total = 128 * N;
  if (i >= total) return;
  int n = i % N;
  float v = 0.f;
#pragma unroll
  for (int z = 0; z < KS; z++) v += P[(size_t)z * total + i];
  v += bias[n];
  if (EPI == 2) v = v > 0.f ? v : 0.f;
  C[i] = v;
}

// ---------------- tiled fp32 GEMM (fallback path only) ----------------
template <int BM_, int BN_, int EPI>
__global__ __launch_bounds__(256)
void gemm_t(const float* __restrict__ A, const float* __restrict__ B,
            float* __restrict__ C, const float* __restrict__ bias,
            int M, int N, int K, int lda, int ldb, int ldc, int accum,
            long bz, long cz) {
  constexpr int MR = BM_ / 16, NR = BN_ / 16;
  __shared__ float As[16][BM_ + 4];
  __shared__ float Bs[16][BN_ + 4];
  const float* Bp = B + (size_t)blockIdx.z * bz;
  float* Cp = C + (size_t)blockIdx.z * cz;
  int tx = threadIdx.x, ty = threadIdx.y;
  int tid = ty * 16 + tx;
  int m0 = blockIdx.y * BM_, n0 = blockIdx.x * BN_;
  float acc[MR][NR] = {};
  for (int k0 = 0; k0 < K; k0 += 16) {
#pragma unroll
    for (int p = 0; p < BM_ / 64; p++) {
      int id = tid + p * 256;
      int r = id >> 2, c4 = (id & 3) * 4;
      int gm = m0 + r;
      float v[4];
      if (gm < M && k0 + c4 + 3 < K) {
        const float4 t4 = *(const float4*)&A[(size_t)gm * lda + k0 + c4];
        v[0] = t4.x; v[1] = t4.y; v[2] = t4.z; v[3] = t4.w;
      } else {
#pragma unroll
        for (int q = 0; q < 4; q++) {
          int gk = k0 + c4 + q;
          v[q] = (gm < M && gk < K) ? A[(size_t)gm * lda + gk] : 0.0f;
        }
      }
#pragma unroll
      for (int q = 0; q < 4; q++) As[c4 + q][r] = v[q];
    }
#pragma unroll
    for (int p = 0; p < BN_ / 64; p++) {
      int id = tid + p * 256;
      int r = id / (BN_ / 4), c4 = (id % (BN_ / 4)) * 4;
      int gk = k0 + r, gn = n0 + c4;
      float v[4];
      if (gk < K && gn + 3 < N) {
        const float4 t4 = *(const float4*)&Bp[(size_t)gk * ldb + gn];
        v[0] = t4.x; v[1] = t4.y; v[2] = t4.z; v[3] = t4.w;
      } else {
#pragma unroll
        for (int q = 0; q < 4; q++)
          v[q] = (gk < K && gn + q < N) ? Bp[(size_t)gk * ldb + gn + q] : 0.0f;
      }
      *(float4*)&Bs[r][c4] = *(const float4*)v;
    }
    __syncthreads();
#pragma unroll
    for (int kk = 0; kk < 16; kk++) {
      float a[MR], b[NR];
#pragma unroll
      for (int q = 0; q < MR / 4; q++)
        *(float4*)&a[q * 4] = *(const float4*)&As[kk][ty * MR + q * 4];
#pragma unroll
      for (int q = 0; q < NR / 4; q++)
        *(float4*)&b[q * 4] = *(const float4*)&Bs[kk][tx * NR + q * 4];
#pragma unroll
      for (int i = 0; i < MR; i++)
#pragma unroll
        for (int j = 0; j < NR; j++) acc[i][j] += a[i] * b[j];
    }
    __syncthreads();
  }
#pragma unroll
  for (int i = 0; i < MR; i++) {
    int gm = m0 + ty * MR + i;
    if (gm >= M) continue;
#pragma unroll
    for (int j = 0; j < NR; j++) {
      int gn = n0 + tx * NR + j;
      if (gn >= N) continue;
      float r = acc[i][j];
      if (accum) r += Cp[(size_t)gm * ldc + gn];
      if (EPI == 2) { r += bias[gn]; r = r > 0.f ? r : 0.f; }
      else if (EPI == 3) { r += bias[gn]; }
      Cp[(size_t)gm * ldc + gn] = r;
    }
  }
}

// ---------------- pooling ----------------

__global__ void pool_prep(const int* __restrict__ batch, int* __restrict__ startg, int* __restrict__ cntg) {
  int n = blockIdx.x * blockDim.x + threadIdx.x;
  if (n >= NN) return;
  int b = batch[n];
  if (n == 0 || batch[n - 1] != b) startg[b] = n;
  atomicAdd(&cntg[b], 1);
}

__global__ void pool_kernel(const float* __restrict__ outb,
                            const int* __restrict__ startg, const int* __restrict__ cntg,
                            float* __restrict__ pooled) {
  int g = blockIdx.x, t = threadIdx.x;
  int st = startg[g], c = cntg[g];
  for (int ch = t; ch < DOUT; ch += 256) {
    float s = 0.f;
    for (int k = 0; k < c; k++) s += outb[(size_t)(st + k) * DOUT + ch];
    pooled[(size_t)g * DOUT + ch] = s / (float)(c > 0 ? c : 1);
  }
}

// ---------------- launch ----------------

static inline int cdiv(int a, int b) { return (a + b - 1) / b; }

extern "C" void kernel_launch(void* const* d_in, const int* in_sizes, int n_in,
                              void* d_out, int out_size, void* d_ws, size_t ws_size,
                              hipStream_t stream) {
  const float* x        = (const float*)d_in[0];
  const int*   ei       = (const int*)d_in[1];
  const int*   batch    = (const int*)d_in[2];
  const float* W_heads  = (const float*)d_in[3];
  const float* a1_heads = (const float*)d_in[4];
  const float* a2_heads = (const float*)d_in[5];
  const float* W_out    = (const float*)d_in[6];
  const float* a1_out   = (const float*)d_in[7];
  const float* a2_out   = (const float*)d_in[8];
  const float* W1       = (const float*)d_in[9];
  const float* b1       = (const float*)d_in[10];
  const float* W2       = (const float*)d_in[11];
  const float* b2       = (const float*)d_in[12];
  float* outd = (float*)d_out;
  (void)in_sizes; (void)n_in; (void)out_size;

  char* w = (char*)d_ws;
  size_t off = 0;
  auto alloc = [&](size_t bytes) {
    void* p = w + off;
    off += (bytes + 255) & ~(size_t)255;
    return p;
  };
  auto al = [](size_t b) { return (b + 255) & ~(size_t)255; };

  // common small buffers
  unsigned char* mask = (unsigned char*)alloc((size_t)NN * NN);      // 4 MB
  int*   nbr    = (int*)alloc((size_t)NN * CAP * 4);                 // 1.3 MB
  int*   deg    = (int*)alloc((size_t)NN * 4);
  float* acc    = (float*)alloc((size_t)NN * DOUT * 4);              // 8.2 MB (fallback + MLP partials)
  unsigned short* accb = (unsigned short*)alloc((size_t)NN * DOUT * 2); // 4.1 MB
  float* outb   = (float*)alloc((size_t)NN * DOUT * 4);              // 8.2 MB
  float* f1o    = (float*)alloc((size_t)NN * 4);
  float* f2o    = (float*)alloc((size_t)NN * 4);
  float* cso    = (float*)alloc((size_t)DOUT * 4);
  float* pooled = (float*)alloc((size_t)NG * DOUT * 4);
  float* hid    = (float*)alloc((size_t)NG * MLPD * 4);
  int*   startg = (int*)alloc((size_t)NG * 4);
  int*   cntg   = (int*)alloc((size_t)NG * 4);
  size_t off_common = off;

  // batched-path big buffers
  size_t need_batched = off_common
      + al((size_t)NN * HCAT * 2)           // Whb (bf16) / split-K partials
      + al((size_t)NN * HCAT * 2)           // hcat bf16
      + al((size_t)NPAD * HCAT * 2)         // W_out^T bf16 (padded)
      + al((size_t)NN * FP * 2)             // x bf16
      + al((size_t)NH * HP * FP * 2)        // W_heads^T bf16
      + al((size_t)NN * NH * CAP * 4)       // att_c
      + al((size_t)NH * NN * 4) * 2         // f1_all + f2_all
      + al((size_t)NH * HHID * 4);          // cs_all
  bool batched = ws_size >= need_batched;

  // 1) adjacency mask + CSR (dedupes duplicate edges like .at[].set(1.0))
  zero_words<<<4096, 256, 0, stream>>>((unsigned int*)mask, NN * NN / 4);
  scatter_mask<<<cdiv(NE, 256), 256, 0, stream>>>(ei, mask);
  build_csr<<<NN / 4, 256, 0, stream>>>(mask, nbr, deg);

  if (batched) {
    unsigned short* Whb   = (unsigned short*)alloc((size_t)NN * HCAT * 2);  // 49.2 MB
    unsigned short* hcatb = (unsigned short*)alloc((size_t)NN * HCAT * 2);  // 49.2 MB
    unsigned short* Wt    = (unsigned short*)alloc((size_t)NPAD * HCAT * 2);// 24.6 MB
    unsigned short* xb    = (unsigned short*)alloc((size_t)NN * FP * 2);    // 1.3 MB
    unsigned short* Wth   = (unsigned short*)alloc((size_t)NH * HP * FP * 2);// 8.2 MB
    float* att_c  = (float*)alloc((size_t)NN * NH * CAP * 4);               // 26.2 MB
    float* f1a    = (float*)alloc((size_t)NH * NN * 4);
    float* f2a    = (float*)alloc((size_t)NH * NN * 4);
    float* csa    = (float*)alloc((size_t)NH * HHID * 4);
    // split-K partials reuse Whb's space (dead after spmm_pv):
    // KSPL=6 * NN*DOUT*4 = 49.15 MB <= 49.2 MB
    float* partC = (float*)Whb;

    // 2) Whb = bf16(x @ W_heads[hd]) via MFMA with FUSED f1/f2/csa epilogue
    conv_x_bf16<<<NN, FP, 0, stream>>>(x, xb);
    convT_gen<<<dim3(FP / 32, HP / 32, NH), dim3(32, 8), 0, stream>>>(
        W_heads, Wth, FF, HHID, HHID, (long)FF * HHID, FP, (long)HP * FP);
    // f1a/f2a contiguous (each NH*NN*4, 256-aligned sizes) -> one zero; csa separate
    zero_words<<<80, 256, 0, stream>>>((unsigned int*)f1a, 2 * NH * NN);
    zero_words<<<12, 256, 0, stream>>>((unsigned int*)csa, NH * HHID);
    gemm_bf16_t<FP, FP, HCAT, HHID, 0, FP, 0, 1, unsigned short>
        <<<dim3(HP / 128, NN / 128, NH), 256, 0, stream>>>(
        xb, 0L, Wth, (long)HP * FP, Whb, (long)HHID,
        a1_heads, a2_heads, f1a, f2a, csa);
    // 3b) W_out -> bf16 transposed (B^T layout for contiguous MFMA B-frags)
    convT_gen<<<dim3(HCAT / 32, NPAD / 32, 1), dim3(32, 8), 0, stream>>>(
        W_out, Wt, HCAT, DOUT, DOUT, 0L, HCAT, 0L);
    // 4) softmax precompute + column-chunked PV gather (L2-locality via chunk->XCD pin)
    att_pre<<<dim3(NN, NH / 4), 256, 0, stream>>>(f1a, f2a, nbr, deg, att_c);
    spmm_pv<<<dim3(PVC, NN / PVR), 256, 0, stream>>>(Whb, att_c, nbr, deg, csa, hcatb);
    // 5) acc = hcat @ W_out via bf16 MFMA, split-K=6 (768 blocks, XCD swizzle)
    gemm_bf16_t<HCAT, HCAT, DOUT, DOUT, KCH, HCAT, 1, 0, float>
        <<<dim3(NPAD / 128, NN / 128, KSPL), 256, 0, stream>>>(
        hcatb, 0L, Wt, 0L, partC, (long)NN * DOUT,
        nullptr, nullptr, nullptr, nullptr, nullptr);
    addn_kernel<<<2048, 256, 0, stream>>>(partC, accb);
    // 6) output attention layer (all-bf16 inputs)
    f12_bf16<<<dim3(NN, 1), 64, 0, stream>>>(accb, DOUT, DOUT, a1_out, a2_out, 0, f1o, f2o);
    zero_words<<<1, 256, 0, stream>>>((unsigned int*)cso, DOUT);
    colsum_at_bf16<<<dim3(cdiv(DOUT, 256), NN / 64), 256, 0, stream>>>(accb, DOUT, DOUT, cso);
    spmm_att_o<<<dim3(NN), 128, 0, stream>>>(accb, f1o, f2o, nbr, deg, cso, outb);
  } else {
    // fallback: per-head pipeline (fp32 GEMM + fp32 spmm)
    float* Wh   = (float*)alloc((size_t)NN * HHID * 4);
    float* hout = (float*)alloc((size_t)NN * HHID * 4);
    float* f1   = (float*)alloc((size_t)NN * 4);
    float* f2   = (float*)alloc((size_t)NN * 4);
    float* cs   = (float*)alloc((size_t)HHID * 4);
    zero_words<<<8000, 256, 0, stream>>>((unsigned int*)acc, NN * DOUT);
    for (int hd = 0; hd < NH; hd++) {
      gemm_t<64, 64, 0><<<dim3(cdiv(HHID, 64), cdiv(NN, 64), 1), dim3(16, 16), 0, stream>>>(
          x, W_heads + (size_t)hd * FF * HHID, Wh, nullptr,
          NN, HHID, FF, FF, HHID, HHID, 0, 0L, 0L);
      f12_kernel<<<dim3(NN, 1), 64, 0, stream>>>(Wh, HHID, HHID,
          a1_heads + (size_t)hd * HHID, a2_heads + (size_t)hd * HHID, 0, f1, f2);
      colsum_kernel<<<dim3(cdiv(HHID, 256), 1), 256, 0, stream>>>(Wh, HHID, HHID, cs);
      spmm_att<float><<<dim3(NN, 1), 256, 0, stream>>>(Wh, HHID, HHID, f1, f2,
                                                       nbr, deg, cs, hout, HHID);
      gemm_t<64, 64, 0><<<dim3(cdiv(DOUT, 64), cdiv(NN, 64), 1), dim3(16, 16), 0, stream>>>(
          hout, W_out + (size_t)hd * HHID * DOUT, acc, nullptr,
          NN, DOUT, HHID, HHID, DOUT, DOUT, 1, 0L, 0L);
    }
    conv_f2b<<<2048, 256, 0, stream>>>(acc, accb, NN * DOUT);
    // 6) output attention layer (fp32 logits from acc)
    f12_kernel<<<dim3(NN, 1), 64, 0, stream>>>(acc, DOUT, DOUT, a1_out, a2_out, 0, f1o, f2o);
    zero_words<<<1, 256, 0, stream>>>((unsigned int*)cso, DOUT);
    colsum_at_f32<<<dim3(cdiv(DOUT, 256), NN / 64), 256, 0, stream>>>(acc, DOUT, DOUT, cso);
    spmm_att_o<<<dim3(NN), 128, 0, stream>>>(accb, f1o, f2o, nbr, deg, cso, outb);
  }

  // 7) global mean pool (batch is sorted)
  zero_words<<<1, 256, 0, stream>>>((unsigned int*)startg, NG * 2);  // startg+cntg contiguous
  pool_prep<<<NN / 256, 256, 0, stream>>>(batch, startg, cntg);
  pool_kernel<<<NG, 256, 0, stream>>>(outb, startg, cntg, pooled);

  // 8) MLP head — thin-M split-K GEMMs (acc is dead here in both paths; reuse for partials)
  float* mlpP = acc;   // 8*128*1000*4 = 4.1 MB <= 8.2 MB
  gemm_thin<DOUT, 8><<<dim3(cdiv(MLPD, 64), 8), 256, 0, stream>>>(pooled, W1, mlpP, MLPD);
  thin_reduce<MLPD, 8, 2><<<cdiv(NG * MLPD, 256), 256, 0, stream>>>(mlpP, b1, hid);
  gemm_thin<MLPD, 8><<<dim3(cdiv(NOUTD, 64), 8), 256, 0, stream>>>(hid, W2, mlpP, NOUTD);
  thin_reduce<NOUTD, 8, 3><<<cdiv(NG * NOUTD, 256), 256, 0, stream>>>(mlpP, b2, outd);
}